// Round 13
// baseline (381.283 us; speedup 1.0000x reference)
//
#include <hip/hip_runtime.h>
#include <stdint.h>

#define B4 4
#define NPIX 4096

typedef short sh8 __attribute__((ext_vector_type(8)));
typedef float f4 __attribute__((ext_vector_type(4)));

__device__ __forceinline__ float delu_f(float v){
  return v > 0.f ? __fmaf_rn(10.f, v, 1.f) : __expf(10.f*v);
}
__device__ __forceinline__ unsigned short f2bf(float f){
  unsigned u = __float_as_uint(f);
  u += 0x7fffu + ((u>>16)&1u);
  return (unsigned short)(u>>16);
}
__device__ __forceinline__ float bf2f(unsigned short h){
  return __uint_as_float(((unsigned)h)<<16);
}

// ---------------- generic 64x64x16 f32 tile GEMM (weight-compose only) ----------------
__global__ __launch_bounds__(256) void gemm_f32(
    const float* __restrict__ W, const float* __restrict__ bias,
    const float* __restrict__ X, long xStride, int ldX,
    float* __restrict__ Out, long outStride, int ldOut,
    int M, int K)
{
  __shared__ float Wt[16][64];
  __shared__ float Xt[16][64];
  const int b  = blockIdx.z;
  const int m0 = blockIdx.y * 64;
  const int n0 = blockIdx.x * 64;
  const int tid = threadIdx.x;
  const int tc = tid & 15, tr = tid >> 4;
  const int wm = tid >> 2, wk = (tid & 3) << 2;
  const int xk = tid >> 4, xn = (tid & 15) << 2;
  const float* Xb = X + (long)b * xStride;
  float acc[4][4] = {};

  for (int k0 = 0; k0 < K; k0 += 16) {
    float4 wv4;
    if (m0 + wm < M) wv4 = *reinterpret_cast<const float4*>(W + (long)(m0+wm)*K + k0 + wk);
    else wv4 = make_float4(0.f,0.f,0.f,0.f);
    Wt[wk+0][wm] = wv4.x; Wt[wk+1][wm] = wv4.y; Wt[wk+2][wm] = wv4.z; Wt[wk+3][wm] = wv4.w;
    *reinterpret_cast<float4*>(&Xt[xk][xn]) =
        *reinterpret_cast<const float4*>(Xb + (long)(k0+xk)*ldX + n0 + xn);
    __syncthreads();
    #pragma unroll
    for (int kk = 0; kk < 16; ++kk) {
      float4 a4 = *reinterpret_cast<const float4*>(&Wt[kk][tr<<2]);
      float4 b4 = *reinterpret_cast<const float4*>(&Xt[kk][tc<<2]);
      float av[4] = {a4.x,a4.y,a4.z,a4.w};
      float bv[4] = {b4.x,b4.y,b4.z,b4.w};
      #pragma unroll
      for (int i=0;i<4;i++)
        #pragma unroll
        for (int j=0;j<4;j++) acc[i][j] = __fmaf_rn(av[i], bv[j], acc[i][j]);
    }
    __syncthreads();
  }

  #pragma unroll
  for (int i=0;i<4;i++){
    int m = m0 + (tr<<2) + i;
    if (m < M) {
      float bv = bias ? bias[m] : 0.f;
      float r[4];
      #pragma unroll
      for (int j=0;j<4;j++) r[j] = acc[i][j] + bv;
      *reinterpret_cast<float4*>(Out + (long)b*outStride + (long)m*ldOut + n0 + (tc<<2)) =
          make_float4(r[0],r[1],r[2],r[3]);
    }
  }
}

// ---------------- bf16 MFMA GEMM: C[m][n] = sum_k W[m][k] * xT[n][k] ----------------
// tile 64(m) x 128(n) x 32(k), 4 waves (2x2).
// EP: 0 = store acc+bias
// EP: 3 = merged lq/lk/lv (M=960): seg0 -> delu colsum to qsum; seg1 -> delu store kl;
//         seg2 -> store vl.
template<int EP, int SPLIT>
__global__ __launch_bounds__(256) void gemm_mfma(
    const unsigned short* __restrict__ Whi, const unsigned short* __restrict__ Wlo,
    const float* __restrict__ bias,
    const unsigned short* __restrict__ Xhi, const unsigned short* __restrict__ Xlo,
    float* __restrict__ Out, long outStride, float* __restrict__ qsum)
{
  __shared__ unsigned short Ah[64][44];
  __shared__ unsigned short Bh[128][44];
  __shared__ unsigned short Al[SPLIT?64:8][44];
  __shared__ unsigned short Bl[SPLIT?128:8][44];
  const int b  = blockIdx.z;
  const int m0 = blockIdx.y * 64;
  const int n0 = blockIdx.x * 128;
  const int tid = threadIdx.x;
  const int sRow = tid >> 2, sK = (tid & 3) << 3;
  const int lane = tid & 63, w = tid >> 6;
  const int wr = w >> 1, wc = w & 1;
  const int fr = lane & 15, fko = (lane >> 4) << 3;

  f4 z4 = {0.f,0.f,0.f,0.f};
  f4 acc[2][4];
  #pragma unroll
  for (int mf=0; mf<2; mf++)
    #pragma unroll
    for (int nf=0; nf<4; nf++) acc[mf][nf] = z4;

  for (int k0 = 0; k0 < 320; k0 += 32) {
    *reinterpret_cast<sh8*>(&Ah[sRow][sK]) =
        *reinterpret_cast<const sh8*>(Whi + (long)(m0+sRow)*320 + k0 + sK);
    if (SPLIT)
      *reinterpret_cast<sh8*>(&Al[sRow][sK]) =
          *reinterpret_cast<const sh8*>(Wlo + (long)(m0+sRow)*320 + k0 + sK);
    #pragma unroll
    for (int r=0; r<2; r++){
      int row = r*64 + sRow;
      long src = ((long)b*NPIX + n0 + row)*320 + k0 + sK;
      *reinterpret_cast<sh8*>(&Bh[row][sK]) = *reinterpret_cast<const sh8*>(Xhi + src);
      if (SPLIT)
        *reinterpret_cast<sh8*>(&Bl[row][sK]) = *reinterpret_cast<const sh8*>(Xlo + src);
    }
    __syncthreads();
    sh8 aH[2], bH[4];
    #pragma unroll
    for (int mf=0; mf<2; mf++)
      aH[mf] = *reinterpret_cast<const sh8*>(&Ah[wr*32 + mf*16 + fr][fko]);
    #pragma unroll
    for (int nf=0; nf<4; nf++)
      bH[nf] = *reinterpret_cast<const sh8*>(&Bh[wc*64 + nf*16 + fr][fko]);
    #pragma unroll
    for (int mf=0; mf<2; mf++)
      #pragma unroll
      for (int nf=0; nf<4; nf++)
        acc[mf][nf] = __builtin_amdgcn_mfma_f32_16x16x32_bf16(aH[mf], bH[nf], acc[mf][nf], 0,0,0);
    if (SPLIT){
      sh8 aL[2], bL[4];
      #pragma unroll
      for (int mf=0; mf<2; mf++)
        aL[mf] = *reinterpret_cast<const sh8*>(&Al[wr*32 + mf*16 + fr][fko]);
      #pragma unroll
      for (int nf=0; nf<4; nf++)
        bL[nf] = *reinterpret_cast<const sh8*>(&Bl[wc*64 + nf*16 + fr][fko]);
      #pragma unroll
      for (int mf=0; mf<2; mf++)
        #pragma unroll
        for (int nf=0; nf<4; nf++){
          acc[mf][nf] = __builtin_amdgcn_mfma_f32_16x16x32_bf16(aL[mf], bH[nf], acc[mf][nf], 0,0,0);
          acc[mf][nf] = __builtin_amdgcn_mfma_f32_16x16x32_bf16(aH[mf], bL[nf], acc[mf][nf], 0,0,0);
        }
    }
    __syncthreads();
  }

  const int orow0 = m0 + wr*32;
  const int ocol  = n0 + wc*64;
  if (EP == 3){
    const int seg = m0 / 320;
    if (seg == 0){
      #pragma unroll
      for (int nf=0; nf<4; nf++){
        float s = 0.f;
        #pragma unroll
        for (int mf=0; mf<2; mf++)
          #pragma unroll
          for (int r=0; r<4; r++)
            s += delu_f(acc[mf][nf][r] + bias[orow0 + mf*16 + ((lane>>4)<<2) + r]);
        s += __shfl_xor(s, 16, 64);
        s += __shfl_xor(s, 32, 64);
        if (lane < 16) atomicAdd(&qsum[(long)b*NPIX + ocol + nf*16 + fr], s);
      }
    } else {
      const int mseg0 = m0 - seg*320 + wr*32;
      long base = (long)b*outStride + (seg == 2 ? 320L*NPIX : 0);
      #pragma unroll
      for (int mf=0; mf<2; mf++)
        #pragma unroll
        for (int r=0; r<4; r++){
          int rowI = mseg0 + mf*16 + ((lane>>4)<<2) + r;
          float bv = bias[seg*320 + rowI];
          #pragma unroll
          for (int nf=0; nf<4; nf++){
            float v = acc[mf][nf][r] + bv;
            if (seg == 1) v = delu_f(v);
            Out[base + (long)rowI*NPIX + ocol + nf*16 + fr] = v;
          }
        }
    }
  } else {
    #pragma unroll
    for (int mf=0; mf<2; mf++)
      #pragma unroll
      for (int r=0; r<4; r++){
        int row = orow0 + mf*16 + ((lane>>4)<<2) + r;
        float bv = bias ? bias[row] : 0.f;
        #pragma unroll
        for (int nf=0; nf<4; nf++){
          float v = acc[mf][nf][r] + bv;
          Out[(long)b*outStride + (long)row*NPIX + ocol + nf*16 + fr] = v;
        }
      }
  }
}

// ---------------- x-build MFMA (merged swin+res segments): grid (3, 64, B4) ----------------
// blockIdx.x < 2: swin segment (cOff 0, K=192, n-tile = x*128); x==2: res (cOff 192, K=128).
__global__ __launch_bounds__(256) void xbuild_mfma(
    const unsigned short* __restrict__ inThi, const unsigned short* __restrict__ inTlo,
    const unsigned short* __restrict__ wswh, const unsigned short* __restrict__ wswl,
    const unsigned short* __restrict__ wrsh, const unsigned short* __restrict__ wrsl,
    const float* __restrict__ b_swin, const float* __restrict__ b_res,
    unsigned short* __restrict__ xTh, unsigned short* __restrict__ xTl)
{
  __shared__ unsigned short Ah[64][44];
  __shared__ unsigned short Bh[128][44];
  __shared__ unsigned short Al[64][44];
  __shared__ unsigned short Bl[128][44];
  const int b  = blockIdx.z;
  const int m0 = blockIdx.y * 64;
  const int segR = (blockIdx.x == 2);
  const int n0   = segR ? 0 : blockIdx.x * 128;
  const int cOff = segR ? 192 : 0;
  const int K    = segR ? 128 : 192;
  const int outC = K;
  const int tOff = cOff;
  const unsigned short* Wh = segR ? wrsh : wswh;
  const unsigned short* Wl = segR ? wrsl : wswl;
  const float* bias = segR ? b_res : b_swin;
  const int tid = threadIdx.x;
  const int sRow = tid >> 2, sK = (tid & 3) << 3;
  const int lane = tid & 63, w = tid >> 6;
  const int wr = w >> 1, wc = w & 1;
  const int fr = lane & 15, fko = (lane >> 4) << 3;

  f4 z4 = {0.f,0.f,0.f,0.f};
  f4 acc[2][4];
  #pragma unroll
  for (int mf=0; mf<2; mf++)
    #pragma unroll
    for (int nf=0; nf<4; nf++) acc[mf][nf] = z4;

  for (int k0 = 0; k0 < K; k0 += 32) {
    long asrc = ((long)b*NPIX + m0 + sRow)*320 + cOff + k0 + sK;
    *reinterpret_cast<sh8*>(&Ah[sRow][sK]) = *reinterpret_cast<const sh8*>(inThi + asrc);
    *reinterpret_cast<sh8*>(&Al[sRow][sK]) = *reinterpret_cast<const sh8*>(inTlo + asrc);
    #pragma unroll
    for (int r=0; r<2; r++){
      int row = r*64 + sRow;
      sh8 vh = {0,0,0,0,0,0,0,0}, vl = {0,0,0,0,0,0,0,0};
      if (n0 + row < outC){
        vh = *reinterpret_cast<const sh8*>(Wh + (long)(n0+row)*K + k0 + sK);
        vl = *reinterpret_cast<const sh8*>(Wl + (long)(n0+row)*K + k0 + sK);
      }
      *reinterpret_cast<sh8*>(&Bh[row][sK]) = vh;
      *reinterpret_cast<sh8*>(&Bl[row][sK]) = vl;
    }
    __syncthreads();
    sh8 aH[2], aL[2], bH[4], bL[4];
    #pragma unroll
    for (int mf=0; mf<2; mf++){
      aH[mf] = *reinterpret_cast<const sh8*>(&Ah[wr*32 + mf*16 + fr][fko]);
      aL[mf] = *reinterpret_cast<const sh8*>(&Al[wr*32 + mf*16 + fr][fko]);
    }
    #pragma unroll
    for (int nf=0; nf<4; nf++){
      bH[nf] = *reinterpret_cast<const sh8*>(&Bh[wc*64 + nf*16 + fr][fko]);
      bL[nf] = *reinterpret_cast<const sh8*>(&Bl[wc*64 + nf*16 + fr][fko]);
    }
    #pragma unroll
    for (int mf=0; mf<2; mf++)
      #pragma unroll
      for (int nf=0; nf<4; nf++){
        acc[mf][nf] = __builtin_amdgcn_mfma_f32_16x16x32_bf16(aH[mf], bH[nf], acc[mf][nf], 0,0,0);
        acc[mf][nf] = __builtin_amdgcn_mfma_f32_16x16x32_bf16(aH[mf], bL[nf], acc[mf][nf], 0,0,0);
        acc[mf][nf] = __builtin_amdgcn_mfma_f32_16x16x32_bf16(aL[mf], bH[nf], acc[mf][nf], 0,0,0);
      }
    __syncthreads();
  }

  const int opix0 = m0 + wr*32;
  const int ocol  = n0 + wc*64;
  #pragma unroll
  for (int mf=0; mf<2; mf++)
    #pragma unroll
    for (int r=0; r<4; r++){
      int pix = opix0 + mf*16 + ((lane>>4)<<2) + r;
      #pragma unroll
      for (int nf=0; nf<4; nf++){
        int col = ocol + nf*16 + fr;
        if (col < outC){
          float v = acc[mf][nf][r] + bias[col];
          unsigned short h = f2bf(v);
          long o = ((long)b*NPIX + pix)*320 + tOff + col;
          xTh[o] = h;
          xTl[o] = f2bf(v - bf2f(h));
        }
      }
    }
}

// ---------------- kvp via MFMA, K-split ----------------
__global__ __launch_bounds__(256) void kvp_mfma(
    const float* __restrict__ proj1, const float* __restrict__ q8f,
    float* __restrict__ kvp)
{
  __shared__ unsigned short Ah[64][44];
  __shared__ unsigned short Bh[128][44];
  __shared__ unsigned short Al[64][44];
  __shared__ unsigned short Bl[128][44];
  const int b = blockIdx.z;
  const int o0 = blockIdx.x * 128;
  const int kbase = blockIdx.y * 128;
  const int tid = threadIdx.x;
  const int sRow = tid >> 2, sK = (tid & 3) << 3;
  const int lane = tid & 63, w = tid >> 6;
  const int wr = w >> 1, wc = w & 1;
  const int fr = lane & 15, fko = (lane >> 4) << 3;
  const float* k8 = q8f + ((long)b*128 + 40)*NPIX;
  const float* vp = proj1 + (long)b*(320L*NPIX);

  f4 z4 = {0.f,0.f,0.f,0.f};
  f4 acc[2][4];
  #pragma unroll
  for (int mf=0; mf<2; mf++)
    #pragma unroll
    for (int nf=0; nf<4; nf++) acc[mf][nf] = z4;

  for (int k0 = 0; k0 < 128; k0 += 32) {
    {
      float vv[8] = {0,0,0,0,0,0,0,0};
      if (sRow < 40){
        float4 a4 = *reinterpret_cast<const float4*>(k8 + (long)sRow*NPIX + kbase + k0 + sK);
        float4 b4 = *reinterpret_cast<const float4*>(k8 + (long)sRow*NPIX + kbase + k0 + sK + 4);
        vv[0]=a4.x; vv[1]=a4.y; vv[2]=a4.z; vv[3]=a4.w;
        vv[4]=b4.x; vv[5]=b4.y; vv[6]=b4.z; vv[7]=b4.w;
      }
      #pragma unroll
      for (int i=0;i<8;i++){
        unsigned short h = f2bf(vv[i]);
        Ah[sRow][sK+i] = h;
        Al[sRow][sK+i] = f2bf(vv[i] - bf2f(h));
      }
    }
    #pragma unroll
    for (int r=0;r<2;r++){
      int row = r*64 + sRow;
      int o = o0 + row;
      float vv[8] = {0,0,0,0,0,0,0,0};
      if (o < 160){
        float4 v4a = *reinterpret_cast<const float4*>(vp + (long)o*NPIX + kbase + k0 + sK);
        float4 v4b = *reinterpret_cast<const float4*>(vp + (long)o*NPIX + kbase + k0 + sK + 4);
        vv[0]=v4a.x; vv[1]=v4a.y; vv[2]=v4a.z; vv[3]=v4a.w;
        vv[4]=v4b.x; vv[5]=v4b.y; vv[6]=v4b.z; vv[7]=v4b.w;
      }
      #pragma unroll
      for (int i=0;i<8;i++){
        unsigned short h = f2bf(vv[i]);
        Bh[row][sK+i] = h;
        Bl[row][sK+i] = f2bf(vv[i] - bf2f(h));
      }
    }
    __syncthreads();
    sh8 aH[2], aL[2], bH[4], bL[4];
    #pragma unroll
    for (int mf=0; mf<2; mf++){
      aH[mf] = *reinterpret_cast<const sh8*>(&Ah[wr*32 + mf*16 + fr][fko]);
      aL[mf] = *reinterpret_cast<const sh8*>(&Al[wr*32 + mf*16 + fr][fko]);
    }
    #pragma unroll
    for (int nf=0; nf<4; nf++){
      bH[nf] = *reinterpret_cast<const sh8*>(&Bh[wc*64 + nf*16 + fr][fko]);
      bL[nf] = *reinterpret_cast<const sh8*>(&Bl[wc*64 + nf*16 + fr][fko]);
    }
    #pragma unroll
    for (int mf=0; mf<2; mf++)
      #pragma unroll
      for (int nf=0; nf<4; nf++){
        acc[mf][nf] = __builtin_amdgcn_mfma_f32_16x16x32_bf16(aH[mf], bH[nf], acc[mf][nf], 0,0,0);
        acc[mf][nf] = __builtin_amdgcn_mfma_f32_16x16x32_bf16(aH[mf], bL[nf], acc[mf][nf], 0,0,0);
        acc[mf][nf] = __builtin_amdgcn_mfma_f32_16x16x32_bf16(aL[mf], bH[nf], acc[mf][nf], 0,0,0);
      }
    __syncthreads();
  }

  const int orow0 = wr*32;
  const int ocol  = o0 + wc*64;
  #pragma unroll
  for (int mf=0; mf<2; mf++)
    #pragma unroll
    for (int r=0; r<4; r++){
      int row = orow0 + mf*16 + ((lane>>4)<<2) + r;
      if (row < 40){
        #pragma unroll
        for (int nf=0; nf<4; nf++){
          int col = ocol + nf*16 + fr;
          if (col < 160)
            atomicAdd(&kvp[((long)b*40 + row)*160 + col], acc[mf][nf][r]);
        }
      }
    }
}

// ---------------- MERGED final + conv: out = outacc + cL*nl*(W2@pT) + cA*na*(kvpT@q8) + conv ----
// grid (32, 3, B4), 256 thr. LDS union: final layout (33.8 KB) / conv layout (54.3 KB).
__global__ __launch_bounds__(256) void final_conv_mfma(
    const unsigned short* __restrict__ W2h,
    const unsigned short* __restrict__ pT,
    const float* __restrict__ kvp,
    const float* __restrict__ q8f,
    const float* __restrict__ proj1,
    const float* __restrict__ norm_a, const float* __restrict__ norm_l,
    const float* __restrict__ ag, const float* __restrict__ lg,
    const unsigned short* __restrict__ Wd3,   // [192][2880] bf16
    const unsigned short* __restrict__ Xhi,   // [B][4096][320] bf16
    float* __restrict__ Out)
{
  __shared__ unsigned short smem[27168];      // 54336 B
  // final-phase aliases
  unsigned short* AhF = smem;                 // [64][44]
  unsigned short* BhF = smem + 2816;          // [128][44]
  unsigned short* AlF = smem + 8448;          // [64][44]
  unsigned short* BlF = smem + 11264;         // [128][44]
  // conv-phase aliases
  unsigned short* AhC = smem;                 // [64][292]
  unsigned short* BsC = smem + 18688;         // [4*265*8]

  const int b  = blockIdx.z;
  const int m0 = blockIdx.y * 64;
  const int n0 = blockIdx.x * 128;
  const int h0 = n0 >> 6;
  const int tid = threadIdx.x;
  const int sRow = tid >> 2, sK = (tid & 3) << 3;
  const int lane = tid & 63, w = tid >> 6;
  const int wr = w >> 1, wc = w & 1;
  const int fr = lane & 15, fg = lane >> 4;
  const int fko = fg << 3;

  // conv staging coords + issue first-chunk prefetch NOW (hides under final phases)
  const int sr = tid >> 6;
  const int sw = tid & 63;
  const int hp = h0 - 1 + sr;
  const bool rowok = (hp >= 0) && (hp < 64);
  const sh8 zero8 = {0,0,0,0,0,0,0,0};
  const int arow = tid >> 2;
  const int acol = (tid & 3) << 3;
  sh8 aReg[9], bReg[4];
  {
    const unsigned short* wsrc = Wd3 + (long)(m0+arow)*2880 + acol;
    #pragma unroll
    for (int t=0;t<9;t++) aReg[t] = *reinterpret_cast<const sh8*>(wsrc + t*320);
    const unsigned short* bsrc = Xhi + ((long)b*NPIX + hp*64 + sw)*320;
    #pragma unroll
    for (int g=0; g<4; g++){
      sh8 v = zero8;
      if (rowok) v = *reinterpret_cast<const sh8*>(bsrc + g*8);
      bReg[g] = v;
    }
  }

  f4 z4 = {0.f,0.f,0.f,0.f};
  f4 acc1[2][4], acc2[2][4], accC[2][4];
  #pragma unroll
  for (int mf=0; mf<2; mf++)
    #pragma unroll
    for (int nf=0; nf<4; nf++){ acc1[mf][nf] = z4; acc2[mf][nf] = z4; accC[mf][nf] = z4; }

  // ---- phase 1: W2 @ pT (K=320, single-pass bf16) ----
  for (int k0 = 0; k0 < 320; k0 += 32) {
    sh8 av = zero8;
    if (m0 + sRow < 160)
      av = *reinterpret_cast<const sh8*>(W2h + ((long)b*160 + m0 + sRow)*320 + k0 + sK);
    *reinterpret_cast<sh8*>(&AhF[sRow*44 + sK]) = av;
    #pragma unroll
    for (int r=0; r<2; r++){
      int row = r*64 + sRow;
      *reinterpret_cast<sh8*>(&BhF[row*44 + sK]) =
          *reinterpret_cast<const sh8*>(pT + ((long)b*NPIX + n0 + row)*320 + k0 + sK);
    }
    __syncthreads();
    sh8 aH[2], bH[4];
    #pragma unroll
    for (int mf=0; mf<2; mf++)
      aH[mf] = *reinterpret_cast<const sh8*>(&AhF[(wr*32 + mf*16 + fr)*44 + fko]);
    #pragma unroll
    for (int nf=0; nf<4; nf++)
      bH[nf] = *reinterpret_cast<const sh8*>(&BhF[(wc*64 + nf*16 + fr)*44 + fko]);
    #pragma unroll
    for (int mf=0; mf<2; mf++)
      #pragma unroll
      for (int nf=0; nf<4; nf++)
        acc1[mf][nf] = __builtin_amdgcn_mfma_f32_16x16x32_bf16(aH[mf], bH[nf], acc1[mf][nf], 0,0,0);
    __syncthreads();
  }

  // ---- phase 2: kvp^T @ q8 (K=64, 3-pass hi/lo split) ----
  for (int k0 = 0; k0 < 64; k0 += 32) {
    {
      int m = m0 + sRow;
      #pragma unroll
      for (int i=0;i<8;i++){
        int kk = k0 + sK + i;
        float v = (kk < 40 && m < 160) ? kvp[((long)b*40 + kk)*160 + m] : 0.f;
        unsigned short h = f2bf(v);
        AhF[sRow*44 + sK+i] = h;
        AlF[sRow*44 + sK+i] = f2bf(v - bf2f(h));
      }
    }
    #pragma unroll
    for (int r=0; r<2; r++){
      int row = r*64 + sRow;
      int pix = n0 + row;
      #pragma unroll
      for (int i=0;i<8;i++){
        int kk = k0 + sK + i;
        float v = (kk < 40) ? q8f[((long)b*128 + kk)*NPIX + pix] : 0.f;
        unsigned short h = f2bf(v);
        BhF[row*44 + sK+i] = h;
        BlF[row*44 + sK+i] = f2bf(v - bf2f(h));
      }
    }
    __syncthreads();
    sh8 aH[2], aL[2], bH[4], bL[4];
    #pragma unroll
    for (int mf=0; mf<2; mf++){
      aH[mf] = *reinterpret_cast<const sh8*>(&AhF[(wr*32 + mf*16 + fr)*44 + fko]);
      aL[mf] = *reinterpret_cast<const sh8*>(&AlF[(wr*32 + mf*16 + fr)*44 + fko]);
    }
    #pragma unroll
    for (int nf=0; nf<4; nf++){
      bH[nf] = *reinterpret_cast<const sh8*>(&BhF[(wc*64 + nf*16 + fr)*44 + fko]);
      bL[nf] = *reinterpret_cast<const sh8*>(&BlF[(wc*64 + nf*16 + fr)*44 + fko]);
    }
    #pragma unroll
    for (int mf=0; mf<2; mf++)
      #pragma unroll
      for (int nf=0; nf<4; nf++){
        acc2[mf][nf] = __builtin_amdgcn_mfma_f32_16x16x32_bf16(aH[mf], bH[nf], acc2[mf][nf], 0,0,0);
        acc2[mf][nf] = __builtin_amdgcn_mfma_f32_16x16x32_bf16(aH[mf], bL[nf], acc2[mf][nf], 0,0,0);
        acc2[mf][nf] = __builtin_amdgcn_mfma_f32_16x16x32_bf16(aL[mf], bH[nf], acc2[mf][nf], 0,0,0);
      }
    __syncthreads();
  }

  // ---- phase 3: composed 3x3 conv (round-8 structure) ----
  if (tid < 32){
    int r = tid >> 3;
    int ws = (tid & 4) ? 65 : 0;
    int g = tid & 3;
    *reinterpret_cast<sh8*>(&BsC[((size_t)g*265 + r*66 + ws)*8]) = zero8;
  }
  for (int c0 = 0; c0 < 320; c0 += 32){
    #pragma unroll
    for (int t=0;t<9;t++)
      *reinterpret_cast<sh8*>(&AhC[arow*292 + t*32 + acol]) = aReg[t];
    #pragma unroll
    for (int g=0; g<4; g++)
      *reinterpret_cast<sh8*>(&BsC[((size_t)g*265 + sr*66 + sw + 1)*8]) = bReg[g];
    if (c0 + 32 < 320){
      const unsigned short* wsrc = Wd3 + (long)(m0+arow)*2880 + c0 + 32 + acol;
      #pragma unroll
      for (int t=0;t<9;t++) aReg[t] = *reinterpret_cast<const sh8*>(wsrc + t*320);
      const unsigned short* bsrc = Xhi + ((long)b*NPIX + hp*64 + sw)*320 + c0 + 32;
      #pragma unroll
      for (int g=0; g<4; g++){
        sh8 v = zero8;
        if (rowok) v = *reinterpret_cast<const sh8*>(bsrc + g*8);
        bReg[g] = v;
      }
    }
    __syncthreads();
    #pragma unroll
    for (int t=0; t<9; t++){
      const int dh = t/3 - 1, dw = t%3 - 1;
      sh8 aH[2], bH[4];
      #pragma unroll
      for (int mf=0; mf<2; mf++)
        aH[mf] = *reinterpret_cast<const sh8*>(&AhC[(wr*32 + mf*16 + fr)*292 + t*32 + fko]);
      #pragma unroll
      for (int nf=0; nf<4; nf++){
        int np = wc*64 + nf*16 + fr;
        int lr = (np >> 6) + dh + 1;
        int lw = (np & 63) + dw + 1;
        bH[nf] = *reinterpret_cast<const sh8*>(&BsC[((size_t)fg*265 + lr*66 + lw)*8]);
      }
      #pragma unroll
      for (int mf=0; mf<2; mf++)
        #pragma unroll
        for (int nf=0; nf<4; nf++)
          accC[mf][nf] = __builtin_amdgcn_mfma_f32_16x16x32_bf16(aH[mf], bH[nf], accC[mf][nf], 0,0,0);
    }
    __syncthreads();
  }

  // ---- epilogue: single Out write ----
  const float cA = 0.7f*ag[0], cL = 0.3f*lg[0];
  const int orow0 = m0 + wr*32;
  const int ocol  = n0 + wc*64;
  #pragma unroll
  for (int mf=0; mf<2; mf++)
    #pragma unroll
    for (int r=0; r<4; r++){
      int row = orow0 + mf*16 + ((lane>>4)<<2) + r;
      if (row < 160){
        const float* oa = proj1 + (long)b*(320L*NPIX) + (long)(160+row)*NPIX;
        #pragma unroll
        for (int nf=0; nf<4; nf++){
          int col = ocol + nf*16 + fr;
          Out[((long)b*160 + row)*NPIX + col] =
              oa[col] + cL*norm_l[(long)b*NPIX+col]*acc1[mf][nf][r]
                      + cA*norm_a[(long)b*NPIX+col]*acc2[mf][nf][r]
                      + accC[mf][nf][r];
        }
      }
    }
}

// ---------------- weight composition kernels ----------------
__global__ void compose1_kernel(const float* __restrict__ av_w, const float* __restrict__ ad1_w,
    const float* __restrict__ ld1_w, const float* __restrict__ wc_w,
    const float* __restrict__ ag, const float* __restrict__ lg, float* __restrict__ Wbig1)
{
  int idx = blockIdx.x*256 + threadIdx.x;
  if (idx >= 320*320) return;
  int r = idx / 320, c = idx % 320;
  float cD = 1.4f*ag[0], cL = 0.3f*lg[0];
  if (r < 160) {
    float s = 0.f;
    for (int j=0;j<320;j++) s += wc_w[r*320+j]*av_w[j*320+c];
    Wbig1[idx] = s;
  } else {
    int o = r - 160;
    float s1 = 0.f, s2 = 0.f;
    for (int j=0;j<320;j++){
      float w = wc_w[o*320+j];
      s1 += w*ad1_w[j*320+c];
      s2 += w*ld1_w[j*320+c];
    }
    Wbig1[idx] = 2.f*wc_w[o*320+c] + cD*s1 + cL*s2;
  }
}

__global__ void composeqk_kernel(const float* __restrict__ aq_w, const float* __restrict__ aq_b,
    const float* __restrict__ ak_w, const float* __restrict__ ak_b,
    const float* __restrict__ w_swin, const float* __restrict__ b_swin,
    const float* __restrict__ w_res, const float* __restrict__ b_res,
    double* __restrict__ Wsw, double* __restrict__ Wres, double* __restrict__ bqk)
{
  int idx = blockIdx.x*256 + threadIdx.x;
  if (idx < 80*192){
    int m = idx/192, j = idx%192;
    const float* aw = (m < 40) ? aq_w + m*320 : ak_w + (m-40)*320;
    double s = 0.0;
    for (int i=0;i<192;i++) s += (double)aw[i]*(double)w_swin[i*192+j];
    Wsw[idx] = s;
  }
  int idx2 = idx - 80*192;
  if (idx2 >= 0 && idx2 < 80*128){
    int m = idx2/128, j = idx2%128;
    const float* aw = (m < 40) ? aq_w + m*320 + 192 : ak_w + (m-40)*320 + 192;
    double s = 0.0;
    for (int i=0;i<128;i++) s += (double)aw[i]*(double)w_res[i*128+j];
    Wres[idx2] = s;
  }
  int idx3 = idx - 80*192 - 80*128;
  if (idx3 >= 0 && idx3 < 80){
    int m = idx3;
    const float* aw = (m < 40) ? aq_w + m*320 : ak_w + (m-40)*320;
    double s = (double)((m < 40) ? aq_b[m] : ak_b[m-40]);
    for (int i=0;i<192;i++) s += (double)aw[i]*(double)b_swin[i];
    for (int i=0;i<128;i++) s += (double)aw[192+i]*(double)b_res[i];
    bqk[m] = s;
  }
}

__global__ void t1_kernel(const float* __restrict__ ad3_w, const float* __restrict__ ld3_w,
    const float* __restrict__ ag, const float* __restrict__ lg, float* __restrict__ Wmix)
{
  long idx = (long)blockIdx.x*256 + threadIdx.x;
  if (idx >= 2880L*320) return;
  int k = (int)(idx / 320), c = (int)(idx % 320);
  int t = k / 320, j = k % 320;
  float cD = 1.4f*ag[0], cL = 0.3f*lg[0];
  long src = (long)(j*320 + c)*9 + t;
  Wmix[idx] = cD*ad3_w[src] + cL*ld3_w[src];
}

// ---------------- merged conversions / small weight preps (one launch) ----------------
__global__ void cvt_all_kernel(
    const float* __restrict__ Wbig1, unsigned short* __restrict__ Wb1h, unsigned short* __restrict__ Wb1l,
    const float* __restrict__ lq_w, unsigned short* __restrict__ lqh,
    const float* __restrict__ lk_w, unsigned short* __restrict__ lkh,
    const float* __restrict__ lv_w, unsigned short* __restrict__ lvh,
    const float* __restrict__ Wd3eff, unsigned short* __restrict__ Wd3b,
    const float* __restrict__ w_swin, unsigned short* __restrict__ wswh, unsigned short* __restrict__ wswl,
    const float* __restrict__ w_res, unsigned short* __restrict__ wrsh, unsigned short* __restrict__ wrsl,
    const double* __restrict__ Wsw, const double* __restrict__ Wres, const double* __restrict__ bqk,
    unsigned short* __restrict__ Wqkh, unsigned short* __restrict__ Wqkl, float* __restrict__ biasqk,
    const float* __restrict__ lq_b, const float* __restrict__ lk_b, const float* __restrict__ lv_b,
    float* __restrict__ bias3,
    const float* __restrict__ av_b, const float* __restrict__ ad1_b, const float* __restrict__ ad3_b,
    const float* __restrict__ ld1_b, const float* __restrict__ ld3_b,
    const float* __restrict__ wc_w, const float* __restrict__ wc_b,
    const float* __restrict__ ag, const float* __restrict__ lg, float* __restrict__ bias1)
{
  long idx = (long)blockIdx.x*256 + threadIdx.x;
  if (idx < 102400){
    float v = Wbig1[idx];
    unsigned short h = f2bf(v);
    Wb1h[idx] = h; Wb1l[idx] = f2bf(v - bf2f(h));
    return;
  }
  idx -= 102400;
  if (idx < 102400){ lqh[idx] = f2bf(lq_w[idx]); return; }
  idx -= 102400;
  if (idx < 102400){ lkh[idx] = f2bf(lk_w[idx]); return; }
  idx -= 102400;
  if (idx < 102400){ lvh[idx] = f2bf(lv_w[idx]); return; }
  idx -= 102400;
  if (idx < 552960){
    int row = (int)(idx / 2880);
    Wd3b[idx] = (row < 160) ? f2bf(Wd3eff[idx]) : (unsigned short)0;
    return;
  }
  idx -= 552960;
  if (idx < 36864){
    float v = w_swin[idx];
    unsigned short h = f2bf(v);
    wswh[idx] = h; wswl[idx] = f2bf(v - bf2f(h));
    return;
  }
  idx -= 36864;
  if (idx < 16384){
    float v = w_res[idx];
    unsigned short h = f2bf(v);
    wrsh[idx] = h; wrsl[idx] = f2bf(v - bf2f(h));
    return;
  }
  idx -= 16384;
  if (idx < 40960){
    int row = (int)(idx / 320), col = (int)(idx % 320);
    double v = 0.0;
    if (row < 80) v = (col < 192) ? Wsw[row*192+col] : Wres[row*128+(col-192)];
    float f = (float)v;
    unsigned short h = f2bf(f);
    Wqkh[idx] = h; Wqkl[idx] = f2bf(f - bf2f(h));
    return;
  }
  idx -= 40960;
  if (idx < 128){ biasqk[idx] = (idx < 80) ? (float)bqk[idx] : 0.f; return; }
  idx -= 128;
  if (idx < 960){
    if (idx < 320) bias3[idx] = lq_b[idx];
    else if (idx < 640) bias3[idx] = lk_b[idx-320];
    else bias3[idx] = lv_b[idx-640];
    return;
  }
  idx -= 960;
  if (idx < 320){
    int r = (int)idx;
    float cD = 1.4f*ag[0], cL = 0.3f*lg[0];
    if (r < 160){
      float s = 0.f;
      for (int j=0;j<320;j++) s += wc_w[r*320+j]*av_b[j];
      bias1[r] = s;
    } else {
      int o = r - 160;
      float s = wc_b[o];
      for (int j=0;j<320;j++){
        float w = wc_w[o*320+j];
        s += cD*w*(ad1_b[j]+ad3_b[j]) + cL*w*(ld1_b[j]+ld3_b[j]);
      }
      bias1[r] = s;
    }
  }
}
#define CVT_ALL_TOTAL (102400L*4 + 552960 + 36864 + 16384 + 40960 + 128 + 960 + 320)

// inT: transpose raw inputs + fused fp64 da partial
__global__ __launch_bounds__(256) void inT_kernel(
    const float* __restrict__ swin, const float* __restrict__ resnet,
    const double* __restrict__ wdad, double* __restrict__ dabuf,
    unsigned short* __restrict__ inThi, unsigned short* __restrict__ inTlo)
{
  __shared__ float t[64][65];
  __shared__ double redD[4][64];
  const int b = blockIdx.z, ct = blockIdx.y, n0 = blockIdx.x*64;
  const float* src; int C, cs0;
  if (ct < 3){ src = swin;   C = 192; cs0 = ct*64; }
  else       { src = resnet; C = 128; cs0 = (ct-3)*64; }
  const int dst0 = ct*64;
  const int tid = threadIdx.x;
  #pragma unroll
  for (int it=0; it<16; ++it){
    int idx = it*256 + tid;
    int c = idx >> 6, n = idx & 63;
    t[c][n] = src[((long)b*C + cs0 + c)*NPIX + n0 + n];
  }
  __syncthreads();
  {
    int cg = tid >> 6, n = tid & 63;
    double s = 0.0;
    #pragma unroll
    for (int j=0;j<16;j++){
      int c = cg*16 + j;
      s += wdad[b*320 + dst0 + c] * (double)t[c][n];
    }
    redD[cg][n] = s;
  }
  __syncthreads();
  if (tid < 64){
    double s = redD[0][tid]+redD[1][tid]+redD[2][tid]+redD[3][tid];
    atomicAdd(&dabuf[(long)b*NPIX + n0 + tid], s);
  }
  #pragma unroll
  for (int it=0; it<16; ++it){
    int idx = it*256 + tid;
    int n = idx >> 6, c = idx & 63;
    float v = t[c][n];
    unsigned short h = f2bf(v);
    long o = ((long)b*NPIX + n0 + n)*320 + dst0 + c;
    inThi[o] = h;
    inTlo[o] = f2bf(v - bf2f(h));
  }
}

// pT + fused fp32 dl partial
__global__ __launch_bounds__(256) void pT_kernel(
    const float* __restrict__ projL, const float* __restrict__ colsum,
    unsigned short* __restrict__ pT, float* __restrict__ dlbuf)
{
  __shared__ float t[64][65];
  __shared__ float css[64];
  __shared__ float redF[4][64];
  const int b = blockIdx.z, c0 = blockIdx.y*64, n0 = blockIdx.x*64;
  const float* kl = projL + (long)b*(640L*NPIX);
  const float* vl = kl + 320L*NPIX;
  const int tid = threadIdx.x;
  if (tid < 64) css[tid] = colsum[b*320 + c0 + tid];
  __syncthreads();
  float sdl = 0.f;
  #pragma unroll
  for (int it=0; it<16; ++it){
    int idx = it*256 + tid;
    int c = idx >> 6, n = idx & 63;
    long s = (long)(c0+c)*NPIX + n0 + n;
    float klv = kl[s];
    t[c][n] = klv*vl[s];
    sdl = __fmaf_rn(css[c], klv, sdl);
  }
  redF[tid>>6][tid&63] = sdl;
  __syncthreads();
  if (tid < 64)
    atomicAdd(&dlbuf[(long)b*NPIX + n0 + tid],
              redF[0][tid]+redF[1][tid]+redF[2][tid]+redF[3][tid]);
  #pragma unroll
  for (int it=0; it<16; ++it){
    int idx = it*256 + tid;
    int n = idx >> 6, c = idx & 63;
    pT[((long)b*NPIX + n0 + n)*320 + c0 + c] = f2bf(t[c][n]);
  }
}

// merged: normfin + w2
__global__ void fin2_kernel(const double* __restrict__ dabuf, const double* __restrict__ cdad,
    const float* __restrict__ dlbuf, float* __restrict__ norm_a, float* __restrict__ norm_l,
    const float* __restrict__ wc_w, const float* __restrict__ colsum,
    unsigned short* __restrict__ W2h)
{
  long idx = (long)blockIdx.x*256 + threadIdx.x;
  if (idx < B4*NPIX){
    int b = (int)(idx >> 12);
    norm_a[idx] = (float)(1.0/(dabuf[idx] + cdad[b]));
    norm_l[idx] = 1.f/(dlbuf[idx] + 1e-10f);
    return;
  }
  idx -= B4*NPIX;
  if (idx < (long)B4*160*320){
    int b = (int)(idx / (160*320));
    int rem = (int)(idx - (long)b*160*320);
    int c = rem % 320;
    W2h[idx] = f2bf(wc_w[rem]*colsum[b*320+c]);
  }
}

// ---------------- fp64 rank-1 denominator path ----------------
__global__ __launch_bounds__(256) void chsum_kernel(
    const float* __restrict__ swin, const float* __restrict__ resnet,
    double* __restrict__ chsumd)
{
  int b = blockIdx.y, c = blockIdx.x;
  const float* row = (c < 192) ? swin + ((long)b*192 + c)*NPIX
                               : resnet + ((long)b*128 + (c-192))*NPIX;
  double s = 0.0;
  for (int n = threadIdx.x; n < NPIX; n += 256) s += (double)row[n];
  __shared__ double sd[256];
  sd[threadIdx.x] = s; __syncthreads();
  for (int o=128; o; o>>=1){ if (threadIdx.x < o) sd[threadIdx.x] += sd[threadIdx.x+o]; __syncthreads(); }
  if (threadIdx.x == 0) chsumd[b*320+c] = sd[0];
}

__global__ __launch_bounds__(320) void skda_kernel(
    const double* __restrict__ Wsw, const double* __restrict__ Wres,
    const double* __restrict__ bqk, const double* __restrict__ chsumd,
    double* __restrict__ wdad, double* __restrict__ cdad)
{
  int b = blockIdx.x;
  __shared__ double sk[40];
  int tid = threadIdx.x;
  if (tid < 40){
    int m = 40 + tid;
    double s = 4096.0 * bqk[m];
    for (int j=0;j<192;j++) s += Wsw[m*192+j]*chsumd[b*320+j];
    for (int j=0;j<128;j++) s += Wres[m*128+j]*chsumd[b*320+192+j];
    sk[tid] = s + 1e-10;
  }
  __syncthreads();
  {
    int c = tid;
    double s = 0.0;
    if (c < 192){ for (int m=0;m<40;m++) s += sk[m]*Wsw[m*192+c]; }
    else        { for (int m=0;m<40;m++) s += sk[m]*Wres[m*128+(c-192)]; }
    wdad[b*320+c] = s;
  }
  if (tid == 0){
    double s = 0.0;
    for (int m=0;m<40;m++) s += sk[m]*bqk[m];
    cdad[b] = s;
  }
}

// ---------------- reductions ----------------
__global__ void colsum_kernel(const float* __restrict__ projL, const float* __restrict__ qsum,
    float* __restrict__ colsum)
{
  int b = blockIdx.y, c = blockIdx.x;
  const float* kl = projL + (long)b*640*NPIX + (long)c*NPIX;
  const float* qs = qsum + (long)b*NPIX;
  double s = 0.0;
  for (int n=threadIdx.x; n<NPIX; n+=256) s += (double)kl[n]*(double)qs[n];
  __shared__ double sd[256];
  sd[threadIdx.x] = s; __syncthreads();
  for (int o=128; o; o>>=1){ if (threadIdx.x < o) sd[threadIdx.x] += sd[threadIdx.x+o]; __syncthreads(); }
  if (threadIdx.x == 0) colsum[b*320+c] = (float)sd[0];
}

extern "C" void kernel_launch(void* const* d_in, const int* in_sizes, int n_in,
                              void* d_out, int out_size, void* d_ws, size_t ws_size,
                              hipStream_t stream)
{
  const float* swin   = (const float*)d_in[0];
  const float* resnet = (const float*)d_in[1];
  const float* w_swin = (const float*)d_in[2];
  const float* b_swin = (const float*)d_in[3];
  const float* w_res  = (const float*)d_in[4];
  const float* b_res  = (const float*)d_in[5];
  const float* aq_w = (const float*)d_in[6];
  const float* aq_b = (const float*)d_in[7];
  const float* ak_w = (const float*)d_in[8];
  const float* ak_b = (const float*)d_in[9];
  const float* av_w = (const float*)d_in[10];
  const float* av_b = (const float*)d_in[11];
  const float* ad1_w = (const float*)d_in[12];
  const float* ad1_b = (const float*)d_in[13];
  const float* ad3_w = (const float*)d_in[14];
  const float* ad3_b = (const float*)d_in[15];
  const float* ag    = (const float*)d_in[16];
  const float* lq_w = (const float*)d_in[17];
  const float* lq_b = (const float*)d_in[18];
  const float* lk_w = (const float*)d_in[19];
  const float* lk_b = (const float*)d_in[20];
  const float* lv_w = (const float*)d_in[21];
  const float* lv_b = (const float*)d_in[22];
  const float* ld1_w = (const float*)d_in[23];
  const float* ld1_b = (const float*)d_in[24];
  const float* ld3_w = (const float*)d_in[25];
  const float* ld3_b = (const float*)d_in[26];
  const float* lg    = (const float*)d_in[27];
  const float* wc_w = (const float*)d_in[28];
  const float* wc_b = (const float*)d_in[29];
  float* out = (float*)d_out;

  // ---- workspace carve (zeroed block first) ----
  char* p = (char*)d_ws;
  double* dabuf = (double*)p; p += (size_t)B4*NPIX*8;
  float* dlbuf  = (float*)p;  p += (size_t)B4*NPIX*4;
  float* qsum   = (float*)p;  p += (size_t)B4*NPIX*4;
  float* kvp    = (float*)p;  p += (size_t)B4*40*160*4;
  size_t zbytes = (size_t)B4*NPIX*8 + (size_t)B4*NPIX*4*2 + (size_t)B4*40*160*4;
  double* Wsw   = (double*)p; p += (size_t)80*192*8;
  double* Wres  = (double*)p; p += (size_t)80*128*8;
  double* bqk   = (double*)p; p += (size_t)80*8;
  double* chsumd= (double*)p; p += (size_t)B4*320*8;
  double* wdad  = (double*)p; p += (size_t)B4*320*8;
  double* cdad  = (double*)p; p += (size_t)B4*8;
  float* q8f    = (float*)p;  p += (size_t)B4*128*NPIX*4;
  float* proj1  = (float*)p;  p += (size_t)B4*320*NPIX*4;  // rows 0..159 vp, 160..319 outacc
  float* projL  = (float*)p;  p += (size_t)B4*640*NPIX*4;  // rows 0..319 kl, 320..639 vl
  float* norm_a = (float*)p;  p += (size_t)B4*NPIX*4;
  float* norm_l = (float*)p;  p += (size_t)B4*NPIX*4;
  float* colsum = (float*)p;  p += (size_t)B4*320*4;
  float* Wbig1  = (float*)p;  p += (size_t)320*320*4;
  float* bias1  = (float*)p;  p += (size_t)320*4;
  float* Wmix   = (float*)p;  p += (size_t)2880*320*4;
  float* Wd3eff = (float*)p;  p += (size_t)160*2880*4;
  float* biasqk = (float*)p;  p += (size_t)128*4;
  float* bias3  = (float*)p;  p += (size_t)960*4;
  p = (char*)(((uintptr_t)p + 255) & ~(uintptr_t)255);
  unsigned short* xTh  = (unsigned short*)p; p += (size_t)B4*NPIX*320*2;
  unsigned short* xTl  = (unsigned short*)p; p += (size_t)B4*NPIX*320*2;
  unsigned short* Wb1h = (unsigned short*)p; p += (size_t)320*320*2;
  unsigned short* Wb1l = (unsigned short*)p; p += (size_t)320*320*2;
  unsigned short* lqh  = (unsigned short*)p; p += (size_t)320*320*2;   // lqh/lkh/lvh contiguous
  unsigned short* lkh  = (unsigned short*)p; p += (size_t)320*320*2;
  unsigned short* lvh  = (unsigned short*)p; p += (size_t)320*320*2;
  unsigned short* Wd3b = (unsigned short*)p; p += (size_t)192*2880*2;
  unsigned short* wswh = (unsigned short*)p; p += (size_t)192*192*2;
  unsigned short* wswl = (unsigned short*)p; p += (size_t)192*192*2;
  unsigned short* wrsh = (unsigned short*)p; p += (size_t)128*128*2;
  unsigned short* wrsl = (unsigned short*)p; p += (size_t)128*128*2;
  unsigned short* Wqkh = (unsigned short*)p; p += (size_t)128*320*2;
  unsigned short* Wqkl = (unsigned short*)p; p += (size_t)128*320*2;
  if ((size_t)(p - (char*)d_ws) > ws_size) return;

  // aliases over dead regions (stream-ordered safety):
  unsigned short* inThi = (unsigned short*)projL;          // dead once lkv writes projL
  unsigned short* inTlo = inThi + (size_t)B4*NPIX*320;
  unsigned short* pT = xTl;                                // dead once proj1 split GEMM done
  unsigned short* W2h = (unsigned short*)Wmix;             // dead once Wd3eff composed

  hipMemsetAsync(dabuf, 0, zbytes, stream);

  // ---- weight composition ----
  composeqk_kernel<<<(80*192 + 80*128 + 80 + 255)/256, 256, 0, stream>>>(
      aq_w, aq_b, ak_w, ak_b, w_swin, b_swin, w_res, b_res, Wsw, Wres, bqk);
  compose1_kernel<<<(320*320 + 255)/256, 256, 0, stream>>>(av_w, ad1_w, ld1_w, wc_w, ag, lg, Wbig1);
  t1_kernel<<<(2880*320 + 255)/256, 256, 0, stream>>>(ad3_w, ld3_w, ag, lg, Wmix);
  gemm_f32<<<dim3(5,3,9), 256, 0, stream>>>(wc_w, nullptr, Wmix, 320L*320, 320,
      Wd3eff, 320, 2880, 160, 320);

  // ---- all bf16 conversions + small bias preps (one launch) ----
  cvt_all_kernel<<<(int)((CVT_ALL_TOTAL + 255)/256), 256, 0, stream>>>(
      Wbig1, Wb1h, Wb1l, lq_w, lqh, lk_w, lkh, lv_w, lvh,
      Wd3eff, Wd3b, w_swin, wswh, wswl, w_res, wrsh, wrsl,
      Wsw, Wres, bqk, Wqkh, Wqkl, biasqk,
      lq_b, lk_b, lv_b, bias3,
      av_b, ad1_b, ad3_b, ld1_b, ld3_b, wc_w, wc_b, ag, lg, bias1);

  // ---- fp64 rank-1 denominator composition (must precede inT) ----
  chsum_kernel<<<dim3(320,4), 256, 0, stream>>>(swin, resnet, chsumd);
  skda_kernel<<<4, 320, 0, stream>>>(Wsw, Wres, bqk, chsumd, wdad, cdad);

  // ---- input transpose (+fused da partial) + x-build (merged) + q8/k8 via MFMA ----
  inT_kernel<<<dim3(64,5,4), 256, 0, stream>>>(swin, resnet, wdad, dabuf, inThi, inTlo);
  xbuild_mfma<<<dim3(3,64,4), 256, 0, stream>>>(inThi, inTlo, wswh, wswl, wrsh, wrsl,
      b_swin, b_res, xTh, xTl);
  gemm_mfma<0,1><<<dim3(32,2,4), 256, 0, stream>>>(Wqkh, Wqkl, biasqk, inThi, inTlo,
      q8f, 128L*NPIX, nullptr);   // before lkv overwrites inT

  // ---- merged lq/lk/lv projection (stacked [960][320]) ----
  gemm_mfma<3,0><<<dim3(32,15,4), 256, 0, stream>>>(lqh, nullptr, bias3, xTh, nullptr,
      projL, 640L*NPIX, qsum);
  // ---- proj1 split GEMM (last: frees xTl for pT alias) ----
  gemm_mfma<0,1><<<dim3(32,5,4), 256, 0, stream>>>(Wb1h, Wb1l, bias1, xTh, xTl,
      proj1, 320L*NPIX, nullptr);

  // ---- reductions ----
  kvp_mfma<<<dim3(2,32,4), 256, 0, stream>>>(proj1, q8f, kvp);
  colsum_kernel<<<dim3(320,4), 256, 0, stream>>>(projL, qsum, colsum);

  // ---- prep for final (pT fuses dl partial), then merged normfin+w2 ----
  pT_kernel<<<dim3(64,5,4), 256, 0, stream>>>(projL, colsum, pT, dlbuf);
  fin2_kernel<<<(int)((B4*NPIX + (long)B4*160*320 + 255)/256), 256, 0, stream>>>(
      dabuf, cdad, dlbuf, norm_a, norm_l, wc_w, colsum, W2h);

  // ---- merged fused epilogue + composed conv (single Out write) ----
  final_conv_mfma<<<dim3(32,3,4), 256, 0, stream>>>(W2h, pT, kvp, q8f, proj1,
      norm_a, norm_l, ag, lg, Wd3b, xTh, out);
}

// Round 14
// 300.598 us; speedup vs baseline: 1.2684x; 1.2684x over previous
//
#include <hip/hip_runtime.h>
#include <stdint.h>

#define B4 4
#define NPIX 4096

typedef short sh8 __attribute__((ext_vector_type(8)));
typedef float f4 __attribute__((ext_vector_type(4)));

__device__ __forceinline__ float delu_f(float v){
  return v > 0.f ? __fmaf_rn(10.f, v, 1.f) : __expf(10.f*v);
}
__device__ __forceinline__ unsigned short f2bf(float f){
  unsigned u = __float_as_uint(f);
  u += 0x7fffu + ((u>>16)&1u);
  return (unsigned short)(u>>16);
}
__device__ __forceinline__ float bf2f(unsigned short h){
  return __uint_as_float(((unsigned)h)<<16);
}

// ---------------- generic 64x64x16 f32 tile GEMM (weight-compose only) ----------------
__global__ __launch_bounds__(256) void gemm_f32(
    const float* __restrict__ W, const float* __restrict__ bias,
    const float* __restrict__ X, long xStride, int ldX,
    float* __restrict__ Out, long outStride, int ldOut,
    int M, int K)
{
  __shared__ float Wt[16][64];
  __shared__ float Xt[16][64];
  const int b  = blockIdx.z;
  const int m0 = blockIdx.y * 64;
  const int n0 = blockIdx.x * 64;
  const int tid = threadIdx.x;
  const int tc = tid & 15, tr = tid >> 4;
  const int wm = tid >> 2, wk = (tid & 3) << 2;
  const int xk = tid >> 4, xn = (tid & 15) << 2;
  const float* Xb = X + (long)b * xStride;
  float acc[4][4] = {};

  for (int k0 = 0; k0 < K; k0 += 16) {
    float4 wv4;
    if (m0 + wm < M) wv4 = *reinterpret_cast<const float4*>(W + (long)(m0+wm)*K + k0 + wk);
    else wv4 = make_float4(0.f,0.f,0.f,0.f);
    Wt[wk+0][wm] = wv4.x; Wt[wk+1][wm] = wv4.y; Wt[wk+2][wm] = wv4.z; Wt[wk+3][wm] = wv4.w;
    *reinterpret_cast<float4*>(&Xt[xk][xn]) =
        *reinterpret_cast<const float4*>(Xb + (long)(k0+xk)*ldX + n0 + xn);
    __syncthreads();
    #pragma unroll
    for (int kk = 0; kk < 16; ++kk) {
      float4 a4 = *reinterpret_cast<const float4*>(&Wt[kk][tr<<2]);
      float4 b4 = *reinterpret_cast<const float4*>(&Xt[kk][tc<<2]);
      float av[4] = {a4.x,a4.y,a4.z,a4.w};
      float bv[4] = {b4.x,b4.y,b4.z,b4.w};
      #pragma unroll
      for (int i=0;i<4;i++)
        #pragma unroll
        for (int j=0;j<4;j++) acc[i][j] = __fmaf_rn(av[i], bv[j], acc[i][j]);
    }
    __syncthreads();
  }

  #pragma unroll
  for (int i=0;i<4;i++){
    int m = m0 + (tr<<2) + i;
    if (m < M) {
      float bv = bias ? bias[m] : 0.f;
      float r[4];
      #pragma unroll
      for (int j=0;j<4;j++) r[j] = acc[i][j] + bv;
      *reinterpret_cast<float4*>(Out + (long)b*outStride + (long)m*ldOut + n0 + (tc<<2)) =
          make_float4(r[0],r[1],r[2],r[3]);
    }
  }
}

// ---------------- bf16 MFMA GEMM: C[m][n] = sum_k W[m][k] * xT[n][k] ----------------
// tile 64(m) x 128(n) x 32(k), 4 waves (2x2).
// EP: 0 = store acc+bias
// EP: 3 = merged lq/lk/lv (M=960): seg0 -> delu colsum to qsum; seg1 -> delu store kl;
//         seg2 -> store vl.
template<int EP, int SPLIT>
__global__ __launch_bounds__(256) void gemm_mfma(
    const unsigned short* __restrict__ Whi, const unsigned short* __restrict__ Wlo,
    const float* __restrict__ bias,
    const unsigned short* __restrict__ Xhi, const unsigned short* __restrict__ Xlo,
    float* __restrict__ Out, long outStride, float* __restrict__ qsum)
{
  __shared__ unsigned short Ah[64][44];
  __shared__ unsigned short Bh[128][44];
  __shared__ unsigned short Al[SPLIT?64:8][44];
  __shared__ unsigned short Bl[SPLIT?128:8][44];
  const int b  = blockIdx.z;
  const int m0 = blockIdx.y * 64;
  const int n0 = blockIdx.x * 128;
  const int tid = threadIdx.x;
  const int sRow = tid >> 2, sK = (tid & 3) << 3;
  const int lane = tid & 63, w = tid >> 6;
  const int wr = w >> 1, wc = w & 1;
  const int fr = lane & 15, fko = (lane >> 4) << 3;

  f4 z4 = {0.f,0.f,0.f,0.f};
  f4 acc[2][4];
  #pragma unroll
  for (int mf=0; mf<2; mf++)
    #pragma unroll
    for (int nf=0; nf<4; nf++) acc[mf][nf] = z4;

  for (int k0 = 0; k0 < 320; k0 += 32) {
    *reinterpret_cast<sh8*>(&Ah[sRow][sK]) =
        *reinterpret_cast<const sh8*>(Whi + (long)(m0+sRow)*320 + k0 + sK);
    if (SPLIT)
      *reinterpret_cast<sh8*>(&Al[sRow][sK]) =
          *reinterpret_cast<const sh8*>(Wlo + (long)(m0+sRow)*320 + k0 + sK);
    #pragma unroll
    for (int r=0; r<2; r++){
      int row = r*64 + sRow;
      long src = ((long)b*NPIX + n0 + row)*320 + k0 + sK;
      *reinterpret_cast<sh8*>(&Bh[row][sK]) = *reinterpret_cast<const sh8*>(Xhi + src);
      if (SPLIT)
        *reinterpret_cast<sh8*>(&Bl[row][sK]) = *reinterpret_cast<const sh8*>(Xlo + src);
    }
    __syncthreads();
    sh8 aH[2], bH[4];
    #pragma unroll
    for (int mf=0; mf<2; mf++)
      aH[mf] = *reinterpret_cast<const sh8*>(&Ah[wr*32 + mf*16 + fr][fko]);
    #pragma unroll
    for (int nf=0; nf<4; nf++)
      bH[nf] = *reinterpret_cast<const sh8*>(&Bh[wc*64 + nf*16 + fr][fko]);
    #pragma unroll
    for (int mf=0; mf<2; mf++)
      #pragma unroll
      for (int nf=0; nf<4; nf++)
        acc[mf][nf] = __builtin_amdgcn_mfma_f32_16x16x32_bf16(aH[mf], bH[nf], acc[mf][nf], 0,0,0);
    if (SPLIT){
      sh8 aL[2], bL[4];
      #pragma unroll
      for (int mf=0; mf<2; mf++)
        aL[mf] = *reinterpret_cast<const sh8*>(&Al[wr*32 + mf*16 + fr][fko]);
      #pragma unroll
      for (int nf=0; nf<4; nf++)
        bL[nf] = *reinterpret_cast<const sh8*>(&Bl[wc*64 + nf*16 + fr][fko]);
      #pragma unroll
      for (int mf=0; mf<2; mf++)
        #pragma unroll
        for (int nf=0; nf<4; nf++){
          acc[mf][nf] = __builtin_amdgcn_mfma_f32_16x16x32_bf16(aL[mf], bH[nf], acc[mf][nf], 0,0,0);
          acc[mf][nf] = __builtin_amdgcn_mfma_f32_16x16x32_bf16(aH[mf], bL[nf], acc[mf][nf], 0,0,0);
        }
    }
    __syncthreads();
  }

  const int orow0 = m0 + wr*32;
  const int ocol  = n0 + wc*64;
  if (EP == 3){
    const int seg = m0 / 320;
    if (seg == 0){
      #pragma unroll
      for (int nf=0; nf<4; nf++){
        float s = 0.f;
        #pragma unroll
        for (int mf=0; mf<2; mf++)
          #pragma unroll
          for (int r=0; r<4; r++)
            s += delu_f(acc[mf][nf][r] + bias[orow0 + mf*16 + ((lane>>4)<<2) + r]);
        s += __shfl_xor(s, 16, 64);
        s += __shfl_xor(s, 32, 64);
        if (lane < 16) atomicAdd(&qsum[(long)b*NPIX + ocol + nf*16 + fr], s);
      }
    } else {
      const int mseg0 = m0 - seg*320 + wr*32;
      long base = (long)b*outStride + (seg == 2 ? 320L*NPIX : 0);
      #pragma unroll
      for (int mf=0; mf<2; mf++)
        #pragma unroll
        for (int r=0; r<4; r++){
          int rowI = mseg0 + mf*16 + ((lane>>4)<<2) + r;
          float bv = bias[seg*320 + rowI];
          #pragma unroll
          for (int nf=0; nf<4; nf++){
            float v = acc[mf][nf][r] + bv;
            if (seg == 1) v = delu_f(v);
            Out[base + (long)rowI*NPIX + ocol + nf*16 + fr] = v;
          }
        }
    }
  } else {
    #pragma unroll
    for (int mf=0; mf<2; mf++)
      #pragma unroll
      for (int r=0; r<4; r++){
        int row = orow0 + mf*16 + ((lane>>4)<<2) + r;
        float bv = bias ? bias[row] : 0.f;
        #pragma unroll
        for (int nf=0; nf<4; nf++){
          float v = acc[mf][nf][r] + bv;
          Out[(long)b*outStride + (long)row*NPIX + ocol + nf*16 + fr] = v;
        }
      }
  }
}

// ---------------- x-build MFMA (merged swin+res segments): grid (3, 64, B4) ----------------
// blockIdx.x < 2: swin segment (cOff 0, K=192, n-tile = x*128); x==2: res (cOff 192, K=128).
__global__ __launch_bounds__(256) void xbuild_mfma(
    const unsigned short* __restrict__ inThi, const unsigned short* __restrict__ inTlo,
    const unsigned short* __restrict__ wswh, const unsigned short* __restrict__ wswl,
    const unsigned short* __restrict__ wrsh, const unsigned short* __restrict__ wrsl,
    const float* __restrict__ b_swin, const float* __restrict__ b_res,
    unsigned short* __restrict__ xTh, unsigned short* __restrict__ xTl)
{
  __shared__ unsigned short Ah[64][44];
  __shared__ unsigned short Bh[128][44];
  __shared__ unsigned short Al[64][44];
  __shared__ unsigned short Bl[128][44];
  const int b  = blockIdx.z;
  const int m0 = blockIdx.y * 64;
  const int segR = (blockIdx.x == 2);
  const int n0   = segR ? 0 : blockIdx.x * 128;
  const int cOff = segR ? 192 : 0;
  const int K    = segR ? 128 : 192;
  const int outC = K;
  const int tOff = cOff;
  const unsigned short* Wh = segR ? wrsh : wswh;
  const unsigned short* Wl = segR ? wrsl : wswl;
  const float* bias = segR ? b_res : b_swin;
  const int tid = threadIdx.x;
  const int sRow = tid >> 2, sK = (tid & 3) << 3;
  const int lane = tid & 63, w = tid >> 6;
  const int wr = w >> 1, wc = w & 1;
  const int fr = lane & 15, fko = (lane >> 4) << 3;

  f4 z4 = {0.f,0.f,0.f,0.f};
  f4 acc[2][4];
  #pragma unroll
  for (int mf=0; mf<2; mf++)
    #pragma unroll
    for (int nf=0; nf<4; nf++) acc[mf][nf] = z4;

  for (int k0 = 0; k0 < K; k0 += 32) {
    long asrc = ((long)b*NPIX + m0 + sRow)*320 + cOff + k0 + sK;
    *reinterpret_cast<sh8*>(&Ah[sRow][sK]) = *reinterpret_cast<const sh8*>(inThi + asrc);
    *reinterpret_cast<sh8*>(&Al[sRow][sK]) = *reinterpret_cast<const sh8*>(inTlo + asrc);
    #pragma unroll
    for (int r=0; r<2; r++){
      int row = r*64 + sRow;
      sh8 vh = {0,0,0,0,0,0,0,0}, vl = {0,0,0,0,0,0,0,0};
      if (n0 + row < outC){
        vh = *reinterpret_cast<const sh8*>(Wh + (long)(n0+row)*K + k0 + sK);
        vl = *reinterpret_cast<const sh8*>(Wl + (long)(n0+row)*K + k0 + sK);
      }
      *reinterpret_cast<sh8*>(&Bh[row][sK]) = vh;
      *reinterpret_cast<sh8*>(&Bl[row][sK]) = vl;
    }
    __syncthreads();
    sh8 aH[2], aL[2], bH[4], bL[4];
    #pragma unroll
    for (int mf=0; mf<2; mf++){
      aH[mf] = *reinterpret_cast<const sh8*>(&Ah[wr*32 + mf*16 + fr][fko]);
      aL[mf] = *reinterpret_cast<const sh8*>(&Al[wr*32 + mf*16 + fr][fko]);
    }
    #pragma unroll
    for (int nf=0; nf<4; nf++){
      bH[nf] = *reinterpret_cast<const sh8*>(&Bh[wc*64 + nf*16 + fr][fko]);
      bL[nf] = *reinterpret_cast<const sh8*>(&Bl[wc*64 + nf*16 + fr][fko]);
    }
    #pragma unroll
    for (int mf=0; mf<2; mf++)
      #pragma unroll
      for (int nf=0; nf<4; nf++){
        acc[mf][nf] = __builtin_amdgcn_mfma_f32_16x16x32_bf16(aH[mf], bH[nf], acc[mf][nf], 0,0,0);
        acc[mf][nf] = __builtin_amdgcn_mfma_f32_16x16x32_bf16(aH[mf], bL[nf], acc[mf][nf], 0,0,0);
        acc[mf][nf] = __builtin_amdgcn_mfma_f32_16x16x32_bf16(aL[mf], bH[nf], acc[mf][nf], 0,0,0);
      }
    __syncthreads();
  }

  const int opix0 = m0 + wr*32;
  const int ocol  = n0 + wc*64;
  #pragma unroll
  for (int mf=0; mf<2; mf++)
    #pragma unroll
    for (int r=0; r<4; r++){
      int pix = opix0 + mf*16 + ((lane>>4)<<2) + r;
      #pragma unroll
      for (int nf=0; nf<4; nf++){
        int col = ocol + nf*16 + fr;
        if (col < outC){
          float v = acc[mf][nf][r] + bias[col];
          unsigned short h = f2bf(v);
          long o = ((long)b*NPIX + pix)*320 + tOff + col;
          xTh[o] = h;
          xTl[o] = f2bf(v - bf2f(h));
        }
      }
    }
}

// ---------------- kvp via MFMA, K-split ----------------
__global__ __launch_bounds__(256) void kvp_mfma(
    const float* __restrict__ proj1, const float* __restrict__ q8f,
    float* __restrict__ kvp)
{
  __shared__ unsigned short Ah[64][44];
  __shared__ unsigned short Bh[128][44];
  __shared__ unsigned short Al[64][44];
  __shared__ unsigned short Bl[128][44];
  const int b = blockIdx.z;
  const int o0 = blockIdx.x * 128;
  const int kbase = blockIdx.y * 128;
  const int tid = threadIdx.x;
  const int sRow = tid >> 2, sK = (tid & 3) << 3;
  const int lane = tid & 63, w = tid >> 6;
  const int wr = w >> 1, wc = w & 1;
  const int fr = lane & 15, fko = (lane >> 4) << 3;
  const float* k8 = q8f + ((long)b*128 + 40)*NPIX;
  const float* vp = proj1 + (long)b*(320L*NPIX);

  f4 z4 = {0.f,0.f,0.f,0.f};
  f4 acc[2][4];
  #pragma unroll
  for (int mf=0; mf<2; mf++)
    #pragma unroll
    for (int nf=0; nf<4; nf++) acc[mf][nf] = z4;

  for (int k0 = 0; k0 < 128; k0 += 32) {
    {
      float vv[8] = {0,0,0,0,0,0,0,0};
      if (sRow < 40){
        float4 a4 = *reinterpret_cast<const float4*>(k8 + (long)sRow*NPIX + kbase + k0 + sK);
        float4 b4 = *reinterpret_cast<const float4*>(k8 + (long)sRow*NPIX + kbase + k0 + sK + 4);
        vv[0]=a4.x; vv[1]=a4.y; vv[2]=a4.z; vv[3]=a4.w;
        vv[4]=b4.x; vv[5]=b4.y; vv[6]=b4.z; vv[7]=b4.w;
      }
      #pragma unroll
      for (int i=0;i<8;i++){
        unsigned short h = f2bf(vv[i]);
        Ah[sRow][sK+i] = h;
        Al[sRow][sK+i] = f2bf(vv[i] - bf2f(h));
      }
    }
    #pragma unroll
    for (int r=0;r<2;r++){
      int row = r*64 + sRow;
      int o = o0 + row;
      float vv[8] = {0,0,0,0,0,0,0,0};
      if (o < 160){
        float4 v4a = *reinterpret_cast<const float4*>(vp + (long)o*NPIX + kbase + k0 + sK);
        float4 v4b = *reinterpret_cast<const float4*>(vp + (long)o*NPIX + kbase + k0 + sK + 4);
        vv[0]=v4a.x; vv[1]=v4a.y; vv[2]=v4a.z; vv[3]=v4a.w;
        vv[4]=v4b.x; vv[5]=v4b.y; vv[6]=v4b.z; vv[7]=v4b.w;
      }
      #pragma unroll
      for (int i=0;i<8;i++){
        unsigned short h = f2bf(vv[i]);
        Bh[row][sK+i] = h;
        Bl[row][sK+i] = f2bf(vv[i] - bf2f(h));
      }
    }
    __syncthreads();
    sh8 aH[2], aL[2], bH[4], bL[4];
    #pragma unroll
    for (int mf=0; mf<2; mf++){
      aH[mf] = *reinterpret_cast<const sh8*>(&Ah[wr*32 + mf*16 + fr][fko]);
      aL[mf] = *reinterpret_cast<const sh8*>(&Al[wr*32 + mf*16 + fr][fko]);
    }
    #pragma unroll
    for (int nf=0; nf<4; nf++){
      bH[nf] = *reinterpret_cast<const sh8*>(&Bh[wc*64 + nf*16 + fr][fko]);
      bL[nf] = *reinterpret_cast<const sh8*>(&Bl[wc*64 + nf*16 + fr][fko]);
    }
    #pragma unroll
    for (int mf=0; mf<2; mf++)
      #pragma unroll
      for (int nf=0; nf<4; nf++){
        acc[mf][nf] = __builtin_amdgcn_mfma_f32_16x16x32_bf16(aH[mf], bH[nf], acc[mf][nf], 0,0,0);
        acc[mf][nf] = __builtin_amdgcn_mfma_f32_16x16x32_bf16(aH[mf], bL[nf], acc[mf][nf], 0,0,0);
        acc[mf][nf] = __builtin_amdgcn_mfma_f32_16x16x32_bf16(aL[mf], bH[nf], acc[mf][nf], 0,0,0);
      }
    __syncthreads();
  }

  const int orow0 = wr*32;
  const int ocol  = o0 + wc*64;
  #pragma unroll
  for (int mf=0; mf<2; mf++)
    #pragma unroll
    for (int r=0; r<4; r++){
      int row = orow0 + mf*16 + ((lane>>4)<<2) + r;
      if (row < 40){
        #pragma unroll
        for (int nf=0; nf<4; nf++){
          int col = ocol + nf*16 + fr;
          if (col < 160)
            atomicAdd(&kvp[((long)b*40 + row)*160 + col], acc[mf][nf][r]);
        }
      }
    }
}

// ---------------- final MFMA ----------------
__global__ __launch_bounds__(256) void final_mfma(
    const unsigned short* __restrict__ W2h,
    const unsigned short* __restrict__ pT,
    const float* __restrict__ kvp,
    const float* __restrict__ q8f,
    const float* __restrict__ proj1,
    const float* __restrict__ norm_a, const float* __restrict__ norm_l,
    const float* __restrict__ ag, const float* __restrict__ lg,
    float* __restrict__ Out)
{
  __shared__ unsigned short Ah[64][44];
  __shared__ unsigned short Bh[128][44];
  __shared__ unsigned short Al[64][44];
  __shared__ unsigned short Bl[128][44];
  const int b  = blockIdx.z;
  const int m0 = blockIdx.y * 64;
  const int n0 = blockIdx.x * 128;
  const int tid = threadIdx.x;
  const int sRow = tid >> 2, sK = (tid & 3) << 3;
  const int lane = tid & 63, w = tid >> 6;
  const int wr = w >> 1, wc = w & 1;
  const int fr = lane & 15, fko = (lane >> 4) << 3;

  f4 z4 = {0.f,0.f,0.f,0.f};
  f4 acc1[2][4], acc2[2][4];
  #pragma unroll
  for (int mf=0; mf<2; mf++)
    #pragma unroll
    for (int nf=0; nf<4; nf++){ acc1[mf][nf] = z4; acc2[mf][nf] = z4; }

  for (int k0 = 0; k0 < 320; k0 += 32) {
    sh8 av = {0,0,0,0,0,0,0,0};
    if (m0 + sRow < 160)
      av = *reinterpret_cast<const sh8*>(W2h + ((long)b*160 + m0 + sRow)*320 + k0 + sK);
    *reinterpret_cast<sh8*>(&Ah[sRow][sK]) = av;
    #pragma unroll
    for (int r=0; r<2; r++){
      int row = r*64 + sRow;
      *reinterpret_cast<sh8*>(&Bh[row][sK]) =
          *reinterpret_cast<const sh8*>(pT + ((long)b*NPIX + n0 + row)*320 + k0 + sK);
    }
    __syncthreads();
    sh8 aH[2], bH[4];
    #pragma unroll
    for (int mf=0; mf<2; mf++)
      aH[mf] = *reinterpret_cast<const sh8*>(&Ah[wr*32 + mf*16 + fr][fko]);
    #pragma unroll
    for (int nf=0; nf<4; nf++)
      bH[nf] = *reinterpret_cast<const sh8*>(&Bh[wc*64 + nf*16 + fr][fko]);
    #pragma unroll
    for (int mf=0; mf<2; mf++)
      #pragma unroll
      for (int nf=0; nf<4; nf++)
        acc1[mf][nf] = __builtin_amdgcn_mfma_f32_16x16x32_bf16(aH[mf], bH[nf], acc1[mf][nf], 0,0,0);
    __syncthreads();
  }

  for (int k0 = 0; k0 < 64; k0 += 32) {
    {
      int m = m0 + sRow;
      #pragma unroll
      for (int i=0;i<8;i++){
        int kk = k0 + sK + i;
        float v = (kk < 40 && m < 160) ? kvp[((long)b*40 + kk)*160 + m] : 0.f;
        unsigned short h = f2bf(v);
        Ah[sRow][sK+i] = h;
        Al[sRow][sK+i] = f2bf(v - bf2f(h));
      }
    }
    #pragma unroll
    for (int r=0; r<2; r++){
      int row = r*64 + sRow;
      int pix = n0 + row;
      #pragma unroll
      for (int i=0;i<8;i++){
        int kk = k0 + sK + i;
        float v = (kk < 40) ? q8f[((long)b*128 + kk)*NPIX + pix] : 0.f;
        unsigned short h = f2bf(v);
        Bh[row][sK+i] = h;
        Bl[row][sK+i] = f2bf(v - bf2f(h));
      }
    }
    __syncthreads();
    sh8 aH[2], aL[2], bH[4], bL[4];
    #pragma unroll
    for (int mf=0; mf<2; mf++){
      aH[mf] = *reinterpret_cast<const sh8*>(&Ah[wr*32 + mf*16 + fr][fko]);
      aL[mf] = *reinterpret_cast<const sh8*>(&Al[wr*32 + mf*16 + fr][fko]);
    }
    #pragma unroll
    for (int nf=0; nf<4; nf++){
      bH[nf] = *reinterpret_cast<const sh8*>(&Bh[wc*64 + nf*16 + fr][fko]);
      bL[nf] = *reinterpret_cast<const sh8*>(&Bl[wc*64 + nf*16 + fr][fko]);
    }
    #pragma unroll
    for (int mf=0; mf<2; mf++)
      #pragma unroll
      for (int nf=0; nf<4; nf++){
        acc2[mf][nf] = __builtin_amdgcn_mfma_f32_16x16x32_bf16(aH[mf], bH[nf], acc2[mf][nf], 0,0,0);
        acc2[mf][nf] = __builtin_amdgcn_mfma_f32_16x16x32_bf16(aH[mf], bL[nf], acc2[mf][nf], 0,0,0);
        acc2[mf][nf] = __builtin_amdgcn_mfma_f32_16x16x32_bf16(aL[mf], bH[nf], acc2[mf][nf], 0,0,0);
      }
    __syncthreads();
  }

  const float cA = 0.7f*ag[0], cL = 0.3f*lg[0];
  const int orow0 = m0 + wr*32;
  const int ocol  = n0 + wc*64;
  #pragma unroll
  for (int mf=0; mf<2; mf++)
    #pragma unroll
    for (int r=0; r<4; r++){
      int row = orow0 + mf*16 + ((lane>>4)<<2) + r;
      if (row < 160){
        const float* oa = proj1 + (long)b*(320L*NPIX) + (long)(160+row)*NPIX;
        #pragma unroll
        for (int nf=0; nf<4; nf++){
          int col = ocol + nf*16 + fr;
          Out[((long)b*160 + row)*NPIX + col] =
              oa[col] + cL*norm_l[(long)b*NPIX+col]*acc1[mf][nf][r]
                      + cA*norm_a[(long)b*NPIX+col]*acc2[mf][nf][r];
        }
      }
    }
}

// ---------------- composed 3x3 conv via MFMA (round-8 proven config) ----
__global__ __launch_bounds__(256) void conv_mfma(
    const unsigned short* __restrict__ Wd3,
    const unsigned short* __restrict__ Xhi,
    float* __restrict__ Out)
{
  __shared__ unsigned short Ah[64][292];
  __shared__ unsigned short Bs[4*265*8];
  const int b  = blockIdx.z;
  const int m0 = blockIdx.y * 64;
  const int n0 = blockIdx.x * 128;
  const int h0 = n0 >> 6;
  const int tid = threadIdx.x;
  const int lane = tid & 63, w = tid >> 6;
  const int wr = w >> 1, wc = w & 1;
  const int fr = lane & 15, fg = lane >> 4;
  const int fko = fg << 3;

  f4 z4 = {0.f,0.f,0.f,0.f};
  f4 acc[2][4];
  #pragma unroll
  for (int mf=0; mf<2; mf++)
    #pragma unroll
    for (int nf=0; nf<4; nf++) acc[mf][nf] = z4;

  const int sr = tid >> 6;
  const int sw = tid & 63;
  const int hp = h0 - 1 + sr;
  const bool rowok = (hp >= 0) && (hp < 64);
  const sh8 zero8 = {0,0,0,0,0,0,0,0};
  if (tid < 32){
    int r = tid >> 3;
    int ws = (tid & 4) ? 65 : 0;
    int g = tid & 3;
    *reinterpret_cast<sh8*>(&Bs[((size_t)g*265 + r*66 + ws)*8]) = zero8;
  }

  const int arow = tid >> 2;
  const int acol = (tid & 3) << 3;

  sh8 aReg[9], bReg[4];
  {
    const unsigned short* wsrc = Wd3 + (long)(m0+arow)*2880 + acol;
    #pragma unroll
    for (int t=0;t<9;t++) aReg[t] = *reinterpret_cast<const sh8*>(wsrc + t*320);
    const unsigned short* bsrc = Xhi + ((long)b*NPIX + hp*64 + sw)*320;
    #pragma unroll
    for (int g=0; g<4; g++){
      sh8 v = zero8;
      if (rowok) v = *reinterpret_cast<const sh8*>(bsrc + g*8);
      bReg[g] = v;
    }
  }

  for (int c0 = 0; c0 < 320; c0 += 32){
    #pragma unroll
    for (int t=0;t<9;t++)
      *reinterpret_cast<sh8*>(&Ah[arow][t*32 + acol]) = aReg[t];
    #pragma unroll
    for (int g=0; g<4; g++)
      *reinterpret_cast<sh8*>(&Bs[((size_t)g*265 + sr*66 + sw + 1)*8]) = bReg[g];
    if (c0 + 32 < 320){
      const unsigned short* wsrc = Wd3 + (long)(m0+arow)*2880 + c0 + 32 + acol;
      #pragma unroll
      for (int t=0;t<9;t++) aReg[t] = *reinterpret_cast<const sh8*>(wsrc + t*320);
      const unsigned short* bsrc = Xhi + ((long)b*NPIX + hp*64 + sw)*320 + c0 + 32;
      #pragma unroll
      for (int g=0; g<4; g++){
        sh8 v = zero8;
        if (rowok) v = *reinterpret_cast<const sh8*>(bsrc + g*8);
        bReg[g] = v;
      }
    }
    __syncthreads();
    #pragma unroll
    for (int t=0; t<9; t++){
      const int dh = t/3 - 1, dw = t%3 - 1;
      sh8 aH[2], bH[4];
      #pragma unroll
      for (int mf=0; mf<2; mf++)
        aH[mf] = *reinterpret_cast<const sh8*>(&Ah[wr*32 + mf*16 + fr][t*32 + fko]);
      #pragma unroll
      for (int nf=0; nf<4; nf++){
        int np = wc*64 + nf*16 + fr;
        int lr = (np >> 6) + dh + 1;
        int lw = (np & 63) + dw + 1;
        bH[nf] = *reinterpret_cast<const sh8*>(&Bs[((size_t)fg*265 + lr*66 + lw)*8]);
      }
      #pragma unroll
      for (int mf=0; mf<2; mf++)
        #pragma unroll
        for (int nf=0; nf<4; nf++)
          acc[mf][nf] = __builtin_amdgcn_mfma_f32_16x16x32_bf16(aH[mf], bH[nf], acc[mf][nf], 0,0,0);
    }
    __syncthreads();
  }

  const int orow0 = m0 + wr*32;
  const int ocol  = n0 + wc*64;
  #pragma unroll
  for (int mf=0; mf<2; mf++)
    #pragma unroll
    for (int r=0; r<4; r++){
      int row = orow0 + mf*16 + ((lane>>4)<<2) + r;
      if (row < 160){
        #pragma unroll
        for (int nf=0; nf<4; nf++){
          long o = ((long)b*160 + row)*NPIX + ocol + nf*16 + fr;
          Out[o] += acc[mf][nf][r];
        }
      }
    }
}

// ---------------- weight composition kernels ----------------
__global__ void compose1_kernel(const float* __restrict__ av_w, const float* __restrict__ ad1_w,
    const float* __restrict__ ld1_w, const float* __restrict__ wc_w,
    const float* __restrict__ ag, const float* __restrict__ lg, float* __restrict__ Wbig1)
{
  int idx = blockIdx.x*256 + threadIdx.x;
  if (idx >= 320*320) return;
  int r = idx / 320, c = idx % 320;
  float cD = 1.4f*ag[0], cL = 0.3f*lg[0];
  if (r < 160) {
    float s = 0.f;
    for (int j=0;j<320;j++) s += wc_w[r*320+j]*av_w[j*320+c];
    Wbig1[idx] = s;
  } else {
    int o = r - 160;
    float s1 = 0.f, s2 = 0.f;
    for (int j=0;j<320;j++){
      float w = wc_w[o*320+j];
      s1 += w*ad1_w[j*320+c];
      s2 += w*ld1_w[j*320+c];
    }
    Wbig1[idx] = 2.f*wc_w[o*320+c] + cD*s1 + cL*s2;
  }
}

__global__ void composeqk_kernel(const float* __restrict__ aq_w, const float* __restrict__ aq_b,
    const float* __restrict__ ak_w, const float* __restrict__ ak_b,
    const float* __restrict__ w_swin, const float* __restrict__ b_swin,
    const float* __restrict__ w_res, const float* __restrict__ b_res,
    double* __restrict__ Wsw, double* __restrict__ Wres, double* __restrict__ bqk)
{
  int idx = blockIdx.x*256 + threadIdx.x;
  if (idx < 80*192){
    int m = idx/192, j = idx%192;
    const float* aw = (m < 40) ? aq_w + m*320 : ak_w + (m-40)*320;
    double s = 0.0;
    for (int i=0;i<192;i++) s += (double)aw[i]*(double)w_swin[i*192+j];
    Wsw[idx] = s;
  }
  int idx2 = idx - 80*192;
  if (idx2 >= 0 && idx2 < 80*128){
    int m = idx2/128, j = idx2%128;
    const float* aw = (m < 40) ? aq_w + m*320 + 192 : ak_w + (m-40)*320 + 192;
    double s = 0.0;
    for (int i=0;i<128;i++) s += (double)aw[i]*(double)w_res[i*128+j];
    Wres[idx2] = s;
  }
  int idx3 = idx - 80*192 - 80*128;
  if (idx3 >= 0 && idx3 < 80){
    int m = idx3;
    const float* aw = (m < 40) ? aq_w + m*320 : ak_w + (m-40)*320;
    double s = (double)((m < 40) ? aq_b[m] : ak_b[m-40]);
    for (int i=0;i<192;i++) s += (double)aw[i]*(double)b_swin[i];
    for (int i=0;i<128;i++) s += (double)aw[192+i]*(double)b_res[i];
    bqk[m] = s;
  }
}

__global__ void t1_kernel(const float* __restrict__ ad3_w, const float* __restrict__ ld3_w,
    const float* __restrict__ ag, const float* __restrict__ lg, float* __restrict__ Wmix)
{
  long idx = (long)blockIdx.x*256 + threadIdx.x;
  if (idx >= 2880L*320) return;
  int k = (int)(idx / 320), c = (int)(idx % 320);
  int t = k / 320, j = k % 320;
  float cD = 1.4f*ag[0], cL = 0.3f*lg[0];
  long src = (long)(j*320 + c)*9 + t;
  Wmix[idx] = cD*ad3_w[src] + cL*ld3_w[src];
}

// ---------------- merged conversions / small weight preps (one launch) ----------------
__global__ void cvt_all_kernel(
    const float* __restrict__ Wbig1, unsigned short* __restrict__ Wb1h, unsigned short* __restrict__ Wb1l,
    const float* __restrict__ lq_w, unsigned short* __restrict__ lqh,
    const float* __restrict__ lk_w, unsigned short* __restrict__ lkh,
    const float* __restrict__ lv_w, unsigned short* __restrict__ lvh,
    const float* __restrict__ Wd3eff, unsigned short* __restrict__ Wd3b,
    const float* __restrict__ w_swin, unsigned short* __restrict__ wswh, unsigned short* __restrict__ wswl,
    const float* __restrict__ w_res, unsigned short* __restrict__ wrsh, unsigned short* __restrict__ wrsl,
    const double* __restrict__ Wsw, const double* __restrict__ Wres, const double* __restrict__ bqk,
    unsigned short* __restrict__ Wqkh, unsigned short* __restrict__ Wqkl, float* __restrict__ biasqk,
    const float* __restrict__ lq_b, const float* __restrict__ lk_b, const float* __restrict__ lv_b,
    float* __restrict__ bias3,
    const float* __restrict__ av_b, const float* __restrict__ ad1_b, const float* __restrict__ ad3_b,
    const float* __restrict__ ld1_b, const float* __restrict__ ld3_b,
    const float* __restrict__ wc_w, const float* __restrict__ wc_b,
    const float* __restrict__ ag, const float* __restrict__ lg, float* __restrict__ bias1)
{
  long idx = (long)blockIdx.x*256 + threadIdx.x;
  if (idx < 102400){
    float v = Wbig1[idx];
    unsigned short h = f2bf(v);
    Wb1h[idx] = h; Wb1l[idx] = f2bf(v - bf2f(h));
    return;
  }
  idx -= 102400;
  if (idx < 102400){ lqh[idx] = f2bf(lq_w[idx]); return; }
  idx -= 102400;
  if (idx < 102400){ lkh[idx] = f2bf(lk_w[idx]); return; }
  idx -= 102400;
  if (idx < 102400){ lvh[idx] = f2bf(lv_w[idx]); return; }
  idx -= 102400;
  if (idx < 552960){
    int row = (int)(idx / 2880);
    Wd3b[idx] = (row < 160) ? f2bf(Wd3eff[idx]) : (unsigned short)0;
    return;
  }
  idx -= 552960;
  if (idx < 36864){
    float v = w_swin[idx];
    unsigned short h = f2bf(v);
    wswh[idx] = h; wswl[idx] = f2bf(v - bf2f(h));
    return;
  }
  idx -= 36864;
  if (idx < 16384){
    float v = w_res[idx];
    unsigned short h = f2bf(v);
    wrsh[idx] = h; wrsl[idx] = f2bf(v - bf2f(h));
    return;
  }
  idx -= 16384;
  if (idx < 40960){
    int row = (int)(idx / 320), col = (int)(idx % 320);
    double v = 0.0;
    if (row < 80) v = (col < 192) ? Wsw[row*192+col] : Wres[row*128+(col-192)];
    float f = (float)v;
    unsigned short h = f2bf(f);
    Wqkh[idx] = h; Wqkl[idx] = f2bf(f - bf2f(h));
    return;
  }
  idx -= 40960;
  if (idx < 128){ biasqk[idx] = (idx < 80) ? (float)bqk[idx] : 0.f; return; }
  idx -= 128;
  if (idx < 960){
    if (idx < 320) bias3[idx] = lq_b[idx];
    else if (idx < 640) bias3[idx] = lk_b[idx-320];
    else bias3[idx] = lv_b[idx-640];
    return;
  }
  idx -= 960;
  if (idx < 320){
    int r = (int)idx;
    float cD = 1.4f*ag[0], cL = 0.3f*lg[0];
    if (r < 160){
      float s = 0.f;
      for (int j=0;j<320;j++) s += wc_w[r*320+j]*av_b[j];
      bias1[r] = s;
    } else {
      int o = r - 160;
      float s = wc_b[o];
      for (int j=0;j<320;j++){
        float w = wc_w[o*320+j];
        s += cD*w*(ad1_b[j]+ad3_b[j]) + cL*w*(ld1_b[j]+ld3_b[j]);
      }
      bias1[r] = s;
    }
  }
}
#define CVT_ALL_TOTAL (102400L*4 + 552960 + 36864 + 16384 + 40960 + 128 + 960 + 320)

// inT: transpose raw inputs + fused fp64 da partial
__global__ __launch_bounds__(256) void inT_kernel(
    const float* __restrict__ swin, const float* __restrict__ resnet,
    const double* __restrict__ wdad, double* __restrict__ dabuf,
    unsigned short* __restrict__ inThi, unsigned short* __restrict__ inTlo)
{
  __shared__ float t[64][65];
  __shared__ double redD[4][64];
  const int b = blockIdx.z, ct = blockIdx.y, n0 = blockIdx.x*64;
  const float* src; int C, cs0;
  if (ct < 3){ src = swin;   C = 192; cs0 = ct*64; }
  else       { src = resnet; C = 128; cs0 = (ct-3)*64; }
  const int dst0 = ct*64;
  const int tid = threadIdx.x;
  #pragma unroll
  for (int it=0; it<16; ++it){
    int idx = it*256 + tid;
    int c = idx >> 6, n = idx & 63;
    t[c][n] = src[((long)b*C + cs0 + c)*NPIX + n0 + n];
  }
  __syncthreads();
  {
    int cg = tid >> 6, n = tid & 63;
    double s = 0.0;
    #pragma unroll
    for (int j=0;j<16;j++){
      int c = cg*16 + j;
      s += wdad[b*320 + dst0 + c] * (double)t[c][n];
    }
    redD[cg][n] = s;
  }
  __syncthreads();
  if (tid < 64){
    double s = redD[0][tid]+redD[1][tid]+redD[2][tid]+redD[3][tid];
    atomicAdd(&dabuf[(long)b*NPIX + n0 + tid], s);
  }
  #pragma unroll
  for (int it=0; it<16; ++it){
    int idx = it*256 + tid;
    int n = idx >> 6, c = idx & 63;
    float v = t[c][n];
    unsigned short h = f2bf(v);
    long o = ((long)b*NPIX + n0 + n)*320 + dst0 + c;
    inThi[o] = h;
    inTlo[o] = f2bf(v - bf2f(h));
  }
}

// pT + fused fp32 dl partial
__global__ __launch_bounds__(256) void pT_kernel(
    const float* __restrict__ projL, const float* __restrict__ colsum,
    unsigned short* __restrict__ pT, float* __restrict__ dlbuf)
{
  __shared__ float t[64][65];
  __shared__ float css[64];
  __shared__ float redF[4][64];
  const int b = blockIdx.z, c0 = blockIdx.y*64, n0 = blockIdx.x*64;
  const float* kl = projL + (long)b*(640L*NPIX);
  const float* vl = kl + 320L*NPIX;
  const int tid = threadIdx.x;
  if (tid < 64) css[tid] = colsum[b*320 + c0 + tid];
  __syncthreads();
  float sdl = 0.f;
  #pragma unroll
  for (int it=0; it<16; ++it){
    int idx = it*256 + tid;
    int c = idx >> 6, n = idx & 63;
    long s = (long)(c0+c)*NPIX + n0 + n;
    float klv = kl[s];
    t[c][n] = klv*vl[s];
    sdl = __fmaf_rn(css[c], klv, sdl);
  }
  redF[tid>>6][tid&63] = sdl;
  __syncthreads();
  if (tid < 64)
    atomicAdd(&dlbuf[(long)b*NPIX + n0 + tid],
              redF[0][tid]+redF[1][tid]+redF[2][tid]+redF[3][tid]);
  #pragma unroll
  for (int it=0; it<16; ++it){
    int idx = it*256 + tid;
    int n = idx >> 6, c = idx & 63;
    pT[((long)b*NPIX + n0 + n)*320 + c0 + c] = f2bf(t[c][n]);
  }
}

// merged: normfin + w2
__global__ void fin2_kernel(const double* __restrict__ dabuf, const double* __restrict__ cdad,
    const float* __restrict__ dlbuf, float* __restrict__ norm_a, float* __restrict__ norm_l,
    const float* __restrict__ wc_w, const float* __restrict__ colsum,
    unsigned short* __restrict__ W2h)
{
  long idx = (long)blockIdx.x*256 + threadIdx.x;
  if (idx < B4*NPIX){
    int b = (int)(idx >> 12);
    norm_a[idx] = (float)(1.0/(dabuf[idx] + cdad[b]));
    norm_l[idx] = 1.f/(dlbuf[idx] + 1e-10f);
    return;
  }
  idx -= B4*NPIX;
  if (idx < (long)B4*160*320){
    int b = (int)(idx / (160*320));
    int rem = (int)(idx - (long)b*160*320);
    int c = rem % 320;
    W2h[idx] = f2bf(wc_w[rem]*colsum[b*320+c]);
  }
}

// ---------------- fp64 rank-1 denominator path ----------------
__global__ __launch_bounds__(256) void chsum_kernel(
    const float* __restrict__ swin, const float* __restrict__ resnet,
    double* __restrict__ chsumd)
{
  int b = blockIdx.y, c = blockIdx.x;
  const float* row = (c < 192) ? swin + ((long)b*192 + c)*NPIX
                               : resnet + ((long)b*128 + (c-192))*NPIX;
  double s = 0.0;
  for (int n = threadIdx.x; n < NPIX; n += 256) s += (double)row[n];
  __shared__ double sd[256];
  sd[threadIdx.x] = s; __syncthreads();
  for (int o=128; o; o>>=1){ if (threadIdx.x < o) sd[threadIdx.x] += sd[threadIdx.x+o]; __syncthreads(); }
  if (threadIdx.x == 0) chsumd[b*320+c] = sd[0];
}

__global__ __launch_bounds__(320) void skda_kernel(
    const double* __restrict__ Wsw, const double* __restrict__ Wres,
    const double* __restrict__ bqk, const double* __restrict__ chsumd,
    double* __restrict__ wdad, double* __restrict__ cdad)
{
  int b = blockIdx.x;
  __shared__ double sk[40];
  int tid = threadIdx.x;
  if (tid < 40){
    int m = 40 + tid;
    double s = 4096.0 * bqk[m];
    for (int j=0;j<192;j++) s += Wsw[m*192+j]*chsumd[b*320+j];
    for (int j=0;j<128;j++) s += Wres[m*128+j]*chsumd[b*320+192+j];
    sk[tid] = s + 1e-10;
  }
  __syncthreads();
  {
    int c = tid;
    double s = 0.0;
    if (c < 192){ for (int m=0;m<40;m++) s += sk[m]*Wsw[m*192+c]; }
    else        { for (int m=0;m<40;m++) s += sk[m]*Wres[m*128+(c-192)]; }
    wdad[b*320+c] = s;
  }
  if (tid == 0){
    double s = 0.0;
    for (int m=0;m<40;m++) s += sk[m]*bqk[m];
    cdad[b] = s;
  }
}

// ---------------- reductions ----------------
__global__ void colsum_kernel(const float* __restrict__ projL, const float* __restrict__ qsum,
    float* __restrict__ colsum)
{
  int b = blockIdx.y, c = blockIdx.x;
  const float* kl = projL + (long)b*640*NPIX + (long)c*NPIX;
  const float* qs = qsum + (long)b*NPIX;
  double s = 0.0;
  for (int n=threadIdx.x; n<NPIX; n+=256) s += (double)kl[n]*(double)qs[n];
  __shared__ double sd[256];
  sd[threadIdx.x] = s; __syncthreads();
  for (int o=128; o; o>>=1){ if (threadIdx.x < o) sd[threadIdx.x] += sd[threadIdx.x+o]; __syncthreads(); }
  if (threadIdx.x == 0) colsum[b*320+c] = (float)sd[0];
}

extern "C" void kernel_launch(void* const* d_in, const int* in_sizes, int n_in,
                              void* d_out, int out_size, void* d_ws, size_t ws_size,
                              hipStream_t stream)
{
  const float* swin   = (const float*)d_in[0];
  const float* resnet = (const float*)d_in[1];
  const float* w_swin = (const float*)d_in[2];
  const float* b_swin = (const float*)d_in[3];
  const float* w_res  = (const float*)d_in[4];
  const float* b_res  = (const float*)d_in[5];
  const float* aq_w = (const float*)d_in[6];
  const float* aq_b = (const float*)d_in[7];
  const float* ak_w = (const float*)d_in[8];
  const float* ak_b = (const float*)d_in[9];
  const float* av_w = (const float*)d_in[10];
  const float* av_b = (const float*)d_in[11];
  const float* ad1_w = (const float*)d_in[12];
  const float* ad1_b = (const float*)d_in[13];
  const float* ad3_w = (const float*)d_in[14];
  const float* ad3_b = (const float*)d_in[15];
  const float* ag    = (const float*)d_in[16];
  const float* lq_w = (const float*)d_in[17];
  const float* lq_b = (const float*)d_in[18];
  const float* lk_w = (const float*)d_in[19];
  const float* lk_b = (const float*)d_in[20];
  const float* lv_w = (const float*)d_in[21];
  const float* lv_b = (const float*)d_in[22];
  const float* ld1_w = (const float*)d_in[23];
  const float* ld1_b = (const float*)d_in[24];
  const float* ld3_w = (const float*)d_in[25];
  const float* ld3_b = (const float*)d_in[26];
  const float* lg    = (const float*)d_in[27];
  const float* wc_w = (const float*)d_in[28];
  const float* wc_b = (const float*)d_in[29];
  float* out = (float*)d_out;

  // ---- workspace carve (zeroed block first: dabuf,dlbuf,qsum,kvp contiguous) ----
  char* p = (char*)d_ws;
  double* dabuf = (double*)p; p += (size_t)B4*NPIX*8;
  float* dlbuf  = (float*)p;  p += (size_t)B4*NPIX*4;
  float* qsum   = (float*)p;  p += (size_t)B4*NPIX*4;
  float* kvp    = (float*)p;  p += (size_t)B4*40*160*4;
  size_t zbytes = (size_t)B4*NPIX*8 + (size_t)B4*NPIX*4*2 + (size_t)B4*40*160*4;
  double* Wsw   = (double*)p; p += (size_t)80*192*8;
  double* Wres  = (double*)p; p += (size_t)80*128*8;
  double* bqk   = (double*)p; p += (size_t)80*8;
  double* chsumd= (double*)p; p += (size_t)B4*320*8;
  double* wdad  = (double*)p; p += (size_t)B4*320*8;
  double* cdad  = (double*)p; p += (size_t)B4*8;
  float* q8f    = (float*)p;  p += (size_t)B4*128*NPIX*4;
  float* proj1  = (float*)p;  p += (size_t)B4*320*NPIX*4;  // rows 0..159 vp, 160..319 outacc
  float* projL  = (float*)p;  p += (size_t)B4*640*NPIX*4;  // rows 0..319 kl, 320..639 vl
  float* norm_a = (float*)p;  p += (size_t)B4*NPIX*4;
  float* norm_l = (float*)p;  p += (size_t)B4*NPIX*4;
  float* colsum = (float*)p;  p += (size_t)B4*320*4;
  float* Wbig1  = (float*)p;  p += (size_t)320*320*4;
  float* bias1  = (float*)p;  p += (size_t)320*4;
  float* Wmix   = (float*)p;  p += (size_t)2880*320*4;
  float* Wd3eff = (float*)p;  p += (size_t)160*2880*4;
  float* biasqk = (float*)p;  p += (size_t)128*4;
  float* bias3  = (float*)p;  p += (size_t)960*4;
  p = (char*)(((uintptr_t)p + 255) & ~(uintptr_t)255);
  unsigned short* xTh  = (unsigned short*)p; p += (size_t)B4*NPIX*320*2;
  unsigned short* xTl  = (unsigned short*)p; p += (size_t)B4*NPIX*320*2;
  unsigned short* Wb1h = (unsigned short*)p; p += (size_t)320*320*2;
  unsigned short* Wb1l = (unsigned short*)p; p += (size_t)320*320*2;
  unsigned short* lqh  = (unsigned short*)p; p += (size_t)320*320*2;   // lqh/lkh/lvh contiguous = [960][320]
  unsigned short* lkh  = (unsigned short*)p; p += (size_t)320*320*2;
  unsigned short* lvh  = (unsigned short*)p; p += (size_t)320*320*2;
  unsigned short* Wd3b = (unsigned short*)p; p += (size_t)192*2880*2;
  unsigned short* wswh = (unsigned short*)p; p += (size_t)192*192*2;
  unsigned short* wswl = (unsigned short*)p; p += (size_t)192*192*2;
  unsigned short* wrsh = (unsigned short*)p; p += (size_t)128*128*2;
  unsigned short* wrsl = (unsigned short*)p; p += (size_t)128*128*2;
  unsigned short* Wqkh = (unsigned short*)p; p += (size_t)128*320*2;
  unsigned short* Wqkl = (unsigned short*)p; p += (size_t)128*320*2;
  if ((size_t)(p - (char*)d_ws) > ws_size) return;

  // aliases over dead regions (stream-ordered safety):
  unsigned short* inThi = (unsigned short*)projL;          // dead once lkv writes projL
  unsigned short* inTlo = inThi + (size_t)B4*NPIX*320;
  unsigned short* pT = xTl;                                // dead once proj1 split GEMM done
  unsigned short* W2h = (unsigned short*)Wmix;             // dead once Wd3eff composed

  hipMemsetAsync(dabuf, 0, zbytes, stream);

  // ---- weight composition ----
  composeqk_kernel<<<(80*192 + 80*128 + 80 + 255)/256, 256, 0, stream>>>(
      aq_w, aq_b, ak_w, ak_b, w_swin, b_swin, w_res, b_res, Wsw, Wres, bqk);
  compose1_kernel<<<(320*320 + 255)/256, 256, 0, stream>>>(av_w, ad1_w, ld1_w, wc_w, ag, lg, Wbig1);
  t1_kernel<<<(2880*320 + 255)/256, 256, 0, stream>>>(ad3_w, ld3_w, ag, lg, Wmix);
  gemm_f32<<<dim3(5,3,9), 256, 0, stream>>>(wc_w, nullptr, Wmix, 320L*320, 320,
      Wd3eff, 320, 2880, 160, 320);

  // ---- all bf16 conversions + small bias preps (one launch) ----
  cvt_all_kernel<<<(int)((CVT_ALL_TOTAL + 255)/256), 256, 0, stream>>>(
      Wbig1, Wb1h, Wb1l, lq_w, lqh, lk_w, lkh, lv_w, lvh,
      Wd3eff, Wd3b, w_swin, wswh, wswl, w_res, wrsh, wrsl,
      Wsw, Wres, bqk, Wqkh, Wqkl, biasqk,
      lq_b, lk_b, lv_b, bias3,
      av_b, ad1_b, ad3_b, ld1_b, ld3_b, wc_w, wc_b, ag, lg, bias1);

  // ---- fp64 rank-1 denominator composition (must precede inT) ----
  chsum_kernel<<<dim3(320,4), 256, 0, stream>>>(swin, resnet, chsumd);
  skda_kernel<<<4, 320, 0, stream>>>(Wsw, Wres, bqk, chsumd, wdad, cdad);

  // ---- input transpose (+fused da partial) + x-build + q8/k8 via MFMA ----
  inT_kernel<<<dim3(64,5,4), 256, 0, stream>>>(swin, resnet, wdad, dabuf, inThi, inTlo);
  xbuild_mfma<<<dim3(3,64,4), 256, 0, stream>>>(inThi, inTlo, wswh, wswl, wrsh, wrsl,
      b_swin, b_res, xTh, xTl);
  gemm_mfma<0,1><<<dim3(32,2,4), 256, 0, stream>>>(Wqkh, Wqkl, biasqk, inThi, inTlo,
      q8f, 128L*NPIX, nullptr);   // before lkv overwrites inT

  // ---- merged lq/lk/lv projection (stacked [960][320]) ----
  gemm_mfma<3,0><<<dim3(32,15,4), 256, 0, stream>>>(lqh, nullptr, bias3, xTh, nullptr,
      projL, 640L*NPIX, qsum);
  // ---- proj1 split GEMM (last: frees xTl for pT alias) ----
  gemm_mfma<0,1><<<dim3(32,5,4), 256, 0, stream>>>(Wb1h, Wb1l, bias1, xTh, xTl,
      proj1, 320L*NPIX, nullptr);

  // ---- reductions ----
  kvp_mfma<<<dim3(2,32,4), 256, 0, stream>>>(proj1, q8f, kvp);
  colsum_kernel<<<dim3(320,4), 256, 0, stream>>>(projL, qsum, colsum);

  // ---- prep for final (pT fuses dl partial), then merged normfin+w2 ----
  pT_kernel<<<dim3(64,5,4), 256, 0, stream>>>(projL, colsum, pT, dlbuf);
  fin2_kernel<<<(int)((B4*NPIX + (long)B4*160*320 + 255)/256), 256, 0, stream>>>(
      dabuf, cdad, dlbuf, norm_a, norm_l, wc_w, colsum, W2h);

  // ---- fused epilogue + composed conv ----
  final_mfma<<<dim3(32,3,4), 256, 0, stream>>>(W2h, pT, kvp, q8f, proj1,
                                               norm_a, norm_l, ag, lg, out);
  conv_mfma<<<dim3(32,3,4), 256, 0, stream>>>(Wd3b, xTh, out);
}